// Round 7
// baseline (184.696 us; speedup 1.0000x reference)
//
#include <hip/hip_runtime.h>
#include <hip/hip_bf16.h>

// Problem constants: B=64, T=N=1024, d=64, k=128.

typedef __attribute__((ext_vector_type(8))) short bfrag;    // 8 x bf16 (4 VGPRs)
typedef __attribute__((ext_vector_type(4))) short bfrag4;   // 4 x bf16 (2 VGPRs)
typedef __attribute__((ext_vector_type(4))) float ffrag;    // 4 x f32 acc

typedef const __attribute__((address_space(1))) unsigned GAS_U;
typedef __attribute__((address_space(3))) unsigned LAS_U;

__device__ __forceinline__ void gload16(const void* g, void* l) {
  // async global->LDS, 16B per lane; LDS dest = wave-uniform base + lane*16
  __builtin_amdgcn_global_load_lds((GAS_U*)g, (LAS_U*)l, 16, 0, 0);
}

__device__ __forceinline__ unsigned short f2b(float f) {
  unsigned u = __builtin_bit_cast(unsigned, f);
  u += 0x7FFFu + ((u >> 16) & 1u);          // RNE f32 -> bf16 (finite inputs)
  return (unsigned short)(u >> 16);
}
__device__ __forceinline__ float b2f(unsigned short h) {
  return __builtin_bit_cast(float, (unsigned)h << 16);
}
__device__ __forceinline__ float ftanh(float x) {
  // tanh(x) = 1 - 2/(2^(x*2*log2e)+1); ~1e-6 abs err
  float e = __builtin_amdgcn_exp2f(x * 2.88539008177792681f);
  return fmaf(-2.0f, __builtin_amdgcn_rcpf(e + 1.0f), 1.0f);
}
// packed bf16 pair {lo in low16, hi in high16}, RNE, single instruction
__device__ __forceinline__ unsigned cvtpk(float lo, float hi) {
  unsigned r;
  asm("v_cvt_pk_bf16_f32 %0, %1, %2" : "=v"(r) : "v"(lo), "v"(hi));
  return r;
}

#define MFMA(a, b, c) __builtin_amdgcn_mfma_f32_16x16x32_bf16((a), (b), (c), 0, 0, 0)

// K=16 MFMA: D[res16][k16] += A[res16][chk16] * B[chk16][k16]
// A lane layout: row=lane&15, chk=(lane>>4)*4+e  == 16x16 D layout => A comes
// straight from the L-phase accumulator (packed bf16), zero shuffling.
__device__ __forceinline__ void mfma16(bfrag4 a, bfrag4 b, ffrag& c) {
  asm volatile("v_mfma_f32_16x16x16_bf16 %0, %1, %2, %0" : "+a"(c) : "v"(a), "v"(b));
}

// Fragged coeff/addterm global layout (per b, per tc-chunk of 32 cols):
//   element (k, t):  tc=t>>5, chk=t&31, ts=chk>>4, g=(chk>>2)&3, e=chk&3,
//                    kt=k>>4, lr=k&15
//   byte = b*262144 + tc*8192 + ts*4096 + kt*512 + g*128 + lr*8 + e*2
// B-frag read (lane l, tile (ts,kt)): addr = ts*4096+kt*512+(l>>4)*128+(l&15)*8
//   -> 4 x 128B blocks per wave read: conflict-free. gload16 source is LINEAR.

// ---------------------------------------------------------------------------
// prep: RWb = bf16(review@Wl)  [B,T,64]
//       Rb  = bf16(Wr@review^T)  FRAGGED layout (above)
//       Pb  = bf16(Wp@post^T)    FRAGGED layout
//       postb = bf16(post)     [B,N,64]
// ---------------------------------------------------------------------------
__global__ __launch_bounds__(256) void prep_kernel(
    const float* __restrict__ review, const float* __restrict__ post,
    const float* __restrict__ Wl, const float* __restrict__ Wr,
    const float* __restrict__ Wp,
    unsigned short* __restrict__ RWb, unsigned short* __restrict__ Rb,
    unsigned short* __restrict__ Pb, unsigned short* __restrict__ postb)
{
  const int chunk = blockIdx.x, b = blockIdx.y, side = blockIdx.z;
  const int tid = threadIdx.x, lane = tid & 63, w = tid >> 6;
  const int lr = lane & 15, lg = lane >> 4;
  const int r0 = chunk * 128;

  __shared__ __align__(16) unsigned short seqs[128][72];  // seq rows [r][d]
  __shared__ __align__(16) unsigned short wgt[128][72];   // Wr or Wp [k][d]
  __shared__ __align__(16) unsigned short wlt[64][72];    // Wl^T [i][d]

  const float* seq = (side == 0) ? review : post;
#pragma unroll
  for (int jj = 0; jj < 8; ++jj) {
    int e = tid + jj * 256;            // r = e>>4, d4 = (e&15)*4
    int r = e >> 4, d4 = (e & 15) * 4;
    float4 v = *(const float4*)(seq + ((size_t)(b * 1024 + r0 + r)) * 64 + d4);
    unsigned lo = ((unsigned)f2b(v.y) << 16) | f2b(v.x);
    unsigned hi = ((unsigned)f2b(v.w) << 16) | f2b(v.z);
    *(uint2*)&seqs[r][d4] = make_uint2(lo, hi);
    if (side == 1)
      *(uint2*)(postb + ((size_t)(b * 1024 + r0 + r)) * 64 + d4) = make_uint2(lo, hi);
  }
  const float* wkd = (side == 0) ? Wr : Wp;
#pragma unroll
  for (int jj = 0; jj < 8; ++jj) {
    int e = tid + jj * 256;
    int k = e >> 4, d4 = (e & 15) * 4;
    float4 v = *(const float4*)(wkd + k * 64 + d4);
    unsigned lo = ((unsigned)f2b(v.y) << 16) | f2b(v.x);
    unsigned hi = ((unsigned)f2b(v.w) << 16) | f2b(v.z);
    *(uint2*)&wgt[k][d4] = make_uint2(lo, hi);
  }
  if (side == 0) {
    for (int i = tid; i < 64 * 64; i += 256) {
      int d = i >> 6, c = i & 63;
      wlt[c][d] = f2b(Wl[d * 64 + c]);
    }
  }
  __syncthreads();

  if (side == 0) {
    // RW = seqs @ Wl : [128 x 64]; wave w owns t in [32w, 32w+32)
    ffrag acc[2][4] = {};
#pragma unroll
    for (int ks = 0; ks < 2; ++ks)
#pragma unroll
      for (int ts = 0; ts < 2; ++ts) {
        bfrag a = *(const bfrag*)&seqs[w * 32 + ts * 16 + lr][ks * 32 + lg * 8];
#pragma unroll
        for (int is = 0; is < 4; ++is) {
          bfrag bb = *(const bfrag*)&wlt[is * 16 + lr][ks * 32 + lg * 8];
          acc[ts][is] = MFMA(a, bb, acc[ts][is]);
        }
      }
#pragma unroll
    for (int ts = 0; ts < 2; ++ts)
#pragma unroll
      for (int is = 0; is < 4; ++is)
#pragma unroll
        for (int j = 0; j < 4; ++j) {
          int t = r0 + w * 32 + ts * 16 + lg * 4 + j;
          int i2 = is * 16 + lr;
          RWb[((size_t)(b * 1024 + t)) * 64 + i2] = f2b(acc[ts][is][j]);
        }
  }
  {
    // R/P = wgt @ seqs^T : [128 k x 128 t]; wave w owns k in [32w, 32w+32)
    // D: rows k = w*32+ksb*16+lg*4+j, cols t = r0 + ts2*16 + lr
    ffrag acc[2][8] = {};
#pragma unroll
    for (int ks = 0; ks < 2; ++ks)
#pragma unroll
      for (int ksb = 0; ksb < 2; ++ksb) {
        bfrag a = *(const bfrag*)&wgt[w * 32 + ksb * 16 + lr][ks * 32 + lg * 8];
#pragma unroll
        for (int ts = 0; ts < 8; ++ts) {
          bfrag bb = *(const bfrag*)&seqs[ts * 16 + lr][ks * 32 + lg * 8];
          acc[ksb][ts] = MFMA(a, bb, acc[ksb][ts]);
        }
      }
    // fragged store:
    //   tc = chunk*4 + (ts2>>1); ts = ts2&1; g = lr>>2; e = lr&3
    //   kt = w*2 + ksb; within-kt row lr' = lg*4+j -> lr'*8 ( = (lr'>>1)*16+(lr'&1)*8 )
    char* dstb = (char*)((side == 0) ? Rb : Pb) + (size_t)b * 262144
                 + (size_t)chunk * 4 * 8192;
#pragma unroll
    for (int ksb = 0; ksb < 2; ++ksb)
#pragma unroll
      for (int ts2 = 0; ts2 < 8; ++ts2) {
        char* base = dstb + (ts2 >> 1) * 8192 + (ts2 & 1) * 4096
                     + (w * 2 + ksb) * 512 + (lr >> 2) * 128 + (lr & 3) * 2;
#pragma unroll
        for (int j = 0; j < 4; ++j)
          *(unsigned short*)(base + (lg * 4 + j) * 8) = f2b(acc[ksb][ts2][j]);
      }
  }
}

// ---------------------------------------------------------------------------
// hz (fused hp+hr), v7: wave-private res strips, L feeds GEMM A-operand
// DIRECTLY from registers via K=16 MFMA (layout identity: 16x16 D == 16x16x16
// A). No ll buffer, no cross-wave data deps, ONE barrier/iter.
//   role 0: z_p (resident=post strip, chunk over t, coeff=R, add=P)
//   role 1: z_r (resident=RW strip, chunk over n, coeff=P, add=R)
// LDS (24576 B): rw0/rw1 @0/@4096 [32 rows][128B] chunk (pre-swz global src)
//                rl0/rl1 @8192/@16384 fragged coeff (LINEAR gload)
// Per iter: stage(tc+1) async; L(tc): 4 ds_read_b128 + 8 MFMA(16x16x32) +
// 16 tanh -> pk regs; GEMM(tc): 16 ds_read_b64 + 32 MFMA(16x16x16), acc[2][8];
// one __syncthreads.
// ---------------------------------------------------------------------------
__global__ __launch_bounds__(256, 4) void hz_kernel(
    const unsigned short* __restrict__ RWb, const unsigned short* __restrict__ Rb,
    const unsigned short* __restrict__ Pb, const unsigned short* __restrict__ postb,
    const float* __restrict__ whp, const float* __restrict__ whr,
    float* __restrict__ zp, float* __restrict__ zr)
{
  const int orig = blockIdx.x;
  const int swz = (orig & 7) * 128 + (orig >> 3);   // XCD-chunked, bijective
  const int strip = swz & 7, pair = swz >> 3;
  const int b = pair & 63, role = pair >> 6;
  const int s0 = strip * 128;
  const int tid = threadIdx.x, lane = tid & 63, w = tid >> 6;
  const int lr = lane & 15, lg = lane >> 4;

  const unsigned short* resident = role ? RWb : postb;
  const unsigned short* chunkseq = role ? postb : RWb;
  const unsigned short* coeff    = role ? Pb : Rb;
  const unsigned short* addterm  = role ? Rb : Pb;
  const float* wh                = role ? whr : whp;
  float* zout                    = role ? zr : zp;

  __shared__ __align__(16) char smem[24576];
  const int woff = w << 10;   // wave-uniform LDS staging base offset

  // chunk staging source (pre-swizzled so linear dest ends up XOR-swizzled)
  const int crow = tid >> 3, cslot = tid & 7;
  const char* csrc = (const char*)chunkseq + (size_t)b * 131072
                     + crow * 128 + ((cslot ^ (crow & 7)) << 4);   // + tc*4096
  // coeff staging source: fragged layout == LDS layout -> pure linear
  const char* ksrc = (const char*)coeff + (size_t)b * 262144 + tid * 16; // + tc*8192

  // ---- loop-invariant resident B-frags (16 VGPRs) ----
  bfrag bb[2][2];   // [ks][rs], res = w*32 + rs*16 + lr
  {
    const char* rbase = (const char*)resident + ((size_t)(b * 1024 + s0)) * 128;
#pragma unroll
    for (int ks = 0; ks < 2; ++ks)
#pragma unroll
      for (int rs = 0; rs < 2; ++rs)
        bb[ks][rs] = *(const bfrag*)(rbase + (w * 32 + rs * 16 + lr) * 128 + ks * 64 + lg * 16);
  }

  // ---- prologue: stage chunk(0) + coeff(0) ----
  gload16(csrc, smem + woff);
  gload16(ksrc, smem + 8192 + woff);
  gload16(ksrc + 4096, smem + 8192 + 4096 + woff);
  __syncthreads();

  ffrag acc[2][8] = {};   // [rs][kt]: res strip private to wave, all 128 k

#pragma unroll 2
  for (int tc = 0; tc < 32; ++tc) {
    const int cur = tc & 1;
    // ---- issue async staging for tc+1 into buf cur^1 ----
    if (tc < 31) {
      const int nb = cur ^ 1;
      gload16(csrc + (size_t)(tc + 1) * 4096, smem + nb * 4096 + woff);
      gload16(ksrc + (size_t)(tc + 1) * 8192, smem + 8192 + nb * 8192 + woff);
      gload16(ksrc + (size_t)(tc + 1) * 8192 + 4096, smem + 8192 + nb * 8192 + 4096 + woff);
    }

    // ---- L-phase(tc): Ltile[chk][res], tanh -> pk regs ----
    const char* rwc = smem + cur * 4096;
    uint2 pk[2][2];   // [ts][rs]; == A-frags of the K=16 GEMM
#pragma unroll
    for (int ts = 0; ts < 2; ++ts) {
      ffrag la[2] = {};
#pragma unroll
      for (int ks = 0; ks < 2; ++ks) {
        const int arow = ts * 16 + lr;
        bfrag a = *(const bfrag*)(rwc + arow * 128 + (((ks * 4 + lg) ^ (arow & 7)) << 4));
        la[0] = MFMA(a, bb[ks][0], la[0]);
        la[1] = MFMA(a, bb[ks][1], la[1]);
      }
#pragma unroll
      for (int rs = 0; rs < 2; ++rs) {
        pk[ts][rs].x = cvtpk(ftanh(la[rs][0]), ftanh(la[rs][1]));
        pk[ts][rs].y = cvtpk(ftanh(la[rs][2]), ftanh(la[rs][3]));
      }
    }

    // ---- GEMM(tc): acc[res][k] += L^T x coeff (K=16 x2), A from pk regs ----
    const char* rlc = smem + 8192 + cur * 8192;
#pragma unroll
    for (int kt = 0; kt < 8; ++kt) {
#pragma unroll
      for (int ts = 0; ts < 2; ++ts) {
        bfrag4 bk = *(const bfrag4*)(rlc + ts * 4096 + kt * 512 + lg * 128 + lr * 8);
        mfma16(__builtin_bit_cast(bfrag4, pk[ts][0]), bk, acc[0][kt]);
        mfma16(__builtin_bit_cast(bfrag4, pk[ts][1]), bk, acc[1][kt]);
      }
    }
    __syncthreads();   // staging drained + buffers retired
  }

  // ---- epilogue: z[res] = sum_k wh[k] * tanh(acc + addterm) ----
  // lane holds acc for k = kt*16 + lr, res = w*32 + rs*16 + lg*4 + j
  float whs[8];
#pragma unroll
  for (int kt = 0; kt < 8; ++kt) whs[kt] = wh[kt * 16 + lr];

  const char* abase = (const char*)addterm + (size_t)b * 262144
                      + (size_t)(strip * 4 + w) * 8192 + lg * 128 + lr * 8;
  float zsum[2][4] = {};
#pragma unroll
  for (int rs = 0; rs < 2; ++rs)
#pragma unroll
    for (int kt = 0; kt < 8; ++kt) {
      uint2 av = *(const uint2*)(abase + rs * 4096 + kt * 512);
      const float whk = whs[kt];
      zsum[rs][0] += whk * ftanh(acc[rs][kt][0] + b2f((unsigned short)(av.x & 0xFFFF)));
      zsum[rs][1] += whk * ftanh(acc[rs][kt][1] + b2f((unsigned short)(av.x >> 16)));
      zsum[rs][2] += whk * ftanh(acc[rs][kt][2] + b2f((unsigned short)(av.y & 0xFFFF)));
      zsum[rs][3] += whk * ftanh(acc[rs][kt][3] + b2f((unsigned short)(av.y >> 16)));
    }
#pragma unroll
  for (int rs = 0; rs < 2; ++rs)
#pragma unroll
    for (int j = 0; j < 4; ++j) {
      float v = zsum[rs][j];
      v += __shfl_xor(v, 1);
      v += __shfl_xor(v, 2);
      v += __shfl_xor(v, 4);
      v += __shfl_xor(v, 8);
      if (lr == 0)
        zout[(size_t)b * 1024 + s0 + w * 32 + rs * 16 + lg * 4 + j] = v;
    }
}

// ---------------------------------------------------------------------------
// final: block (b, side), 1024 threads: softmax(z) -> weighted seq sum -> out
// ---------------------------------------------------------------------------
__global__ __launch_bounds__(1024) void final_kernel(
    const float* __restrict__ review, const float* __restrict__ post,
    const float* __restrict__ zp, const float* __restrict__ zr,
    float* __restrict__ out)
{
  const int b = blockIdx.x, side = blockIdx.y, tid = threadIdx.x;
  const int wid = tid >> 6, lane = tid & 63;
  __shared__ float zl[1024];
  __shared__ float red[16];
  __shared__ float cacc[16][64];

  const float* z = (side == 0) ? zp : zr;
  const float* seq = (side == 0) ? post : review;

  float v = z[(size_t)b * 1024 + tid];
  zl[tid] = v;
  float m = v;
#pragma unroll
  for (int off = 32; off; off >>= 1) m = fmaxf(m, __shfl_xor(m, off));
  if (lane == 0) red[wid] = m;
  __syncthreads();
  m = red[0];
#pragma unroll
  for (int i = 1; i < 16; ++i) m = fmaxf(m, red[i]);
  __syncthreads();

  float e = __expf(v - m);
  zl[tid] = e;
  float sm = e;
#pragma unroll
  for (int off = 32; off; off >>= 1) sm += __shfl_xor(sm, off);
  if (lane == 0) red[wid] = sm;
  __syncthreads();
  sm = red[0];
#pragma unroll
  for (int i = 1; i < 16; ++i) sm += red[i];
  const float inv = 1.0f / sm;

  const int d = lane;
  float a = 0.f;
  for (int n = wid * 64; n < wid * 64 + 64; ++n)
    a += zl[n] * seq[((size_t)(b * 1024 + n)) * 64 + d];
  cacc[wid][d] = a;
  __syncthreads();
  if (tid < 64) {
    float s = 0.f;
#pragma unroll
    for (int g = 0; g < 16; ++g) s += cacc[g][tid];
    out[b * 128 + side * 64 + tid] = s * inv;
  }
}

// ---------------------------------------------------------------------------
extern "C" void kernel_launch(void* const* d_in, const int* in_sizes, int n_in,
                              void* d_out, int out_size, void* d_ws, size_t ws_size,
                              hipStream_t stream) {
  const float* review = (const float*)d_in[0];
  const float* post   = (const float*)d_in[1];
  const float* Wl     = (const float*)d_in[2];
  const float* Wr     = (const float*)d_in[3];
  const float* Wp     = (const float*)d_in[4];
  const float* whr    = (const float*)d_in[5];
  const float* whp    = (const float*)d_in[6];
  float* out = (float*)d_out;

  char* ws = (char*)d_ws;
  unsigned short* RWb   = (unsigned short*)(ws);                        //  8 MiB
  unsigned short* Rb    = (unsigned short*)(ws + (size_t)8  * 1048576); // 16 MiB
  unsigned short* Pb    = (unsigned short*)(ws + (size_t)24 * 1048576); // 16 MiB
  unsigned short* postb = (unsigned short*)(ws + (size_t)40 * 1048576); //  8 MiB
  float* zp = (float*)(ws + (size_t)48 * 1048576);                      // 256 KiB
  float* zr = (float*)(ws + (size_t)48 * 1048576 + 262144);             // 256 KiB

  prep_kernel<<<dim3(8, 64, 2), dim3(256), 0, stream>>>(
      review, post, Wl, Wr, Wp, RWb, Rb, Pb, postb);
  hz_kernel<<<dim3(1024), dim3(256), 0, stream>>>(
      RWb, Rb, Pb, postb, whp, whr, zp, zr);
  final_kernel<<<dim3(64, 2), dim3(1024), 0, stream>>>(
      review, post, zp, zr, out);
}

// Round 8
// 140.410 us; speedup vs baseline: 1.3154x; 1.3154x over previous
//
#include <hip/hip_runtime.h>
#include <hip/hip_bf16.h>

// Problem constants: B=64, T=N=1024, d=64, k=128.

typedef __attribute__((ext_vector_type(8))) short bfrag;    // 8 x bf16 (4 VGPRs)
typedef __attribute__((ext_vector_type(4))) short bfrag4;   // 4 x bf16 (2 VGPRs)
typedef __attribute__((ext_vector_type(4))) float ffrag;    // 4 x f32 acc

typedef const __attribute__((address_space(1))) unsigned GAS_U;
typedef __attribute__((address_space(3))) unsigned LAS_U;

__device__ __forceinline__ void gload16(const void* g, void* l) {
  // async global->LDS, 16B per lane; LDS dest = wave-uniform base + lane*16
  __builtin_amdgcn_global_load_lds((GAS_U*)g, (LAS_U*)l, 16, 0, 0);
}

__device__ __forceinline__ unsigned short f2b(float f) {
  unsigned u = __builtin_bit_cast(unsigned, f);
  u += 0x7FFFu + ((u >> 16) & 1u);          // RNE f32 -> bf16 (finite inputs)
  return (unsigned short)(u >> 16);
}
__device__ __forceinline__ float b2f(unsigned short h) {
  return __builtin_bit_cast(float, (unsigned)h << 16);
}
__device__ __forceinline__ float ftanh(float x) {
  // tanh(x) = 1 - 2/(2^(x*2*log2e)+1); ~1e-6 abs err
  float e = __builtin_amdgcn_exp2f(x * 2.88539008177792681f);
  return fmaf(-2.0f, __builtin_amdgcn_rcpf(e + 1.0f), 1.0f);
}
// packed bf16 pair {lo in low16, hi in high16}, RNE, single instruction
__device__ __forceinline__ unsigned cvtpk(float lo, float hi) {
  unsigned r;
  asm("v_cvt_pk_bf16_f32 %0, %1, %2" : "=v"(r) : "v"(lo), "v"(hi));
  return r;
}

#define MFMA(a, b, c) __builtin_amdgcn_mfma_f32_16x16x32_bf16((a), (b), (c), 0, 0, 0)

// K=16 MFMA: D[res16][k16] += A[res16][chk16] * B[chk16][k16]
// A lane layout == 16x16 D layout => A comes straight from the L-phase
// accumulator (packed bf16), zero shuffling. NOT volatile: pure dataflow.
__device__ __forceinline__ void mfma16(bfrag4 a, bfrag4 b, ffrag& c) {
  asm("v_mfma_f32_16x16x16_bf16 %0, %1, %2, %0" : "+a"(c) : "v"(a), "v"(b));
}

// Fragged coeff/addterm global layout (per b, per tc-chunk of 32 cols):
//   element (k, t):  tc=t>>5, chk=t&31, ts=chk>>4, g=(chk>>2)&3, e=chk&3,
//                    kt=k>>4, lr=k&15
//   byte = b*262144 + tc*8192 + ts*4096 + kt*512 + g*128 + lr*8 + e*2

// ---------------------------------------------------------------------------
// prep: RWb = bf16(review@Wl)  [B,T,64]
//       Rb  = bf16(Wr@review^T)  FRAGGED layout (above)
//       Pb  = bf16(Wp@post^T)    FRAGGED layout
//       postb = bf16(post)     [B,N,64]
// ---------------------------------------------------------------------------
__global__ __launch_bounds__(256) void prep_kernel(
    const float* __restrict__ review, const float* __restrict__ post,
    const float* __restrict__ Wl, const float* __restrict__ Wr,
    const float* __restrict__ Wp,
    unsigned short* __restrict__ RWb, unsigned short* __restrict__ Rb,
    unsigned short* __restrict__ Pb, unsigned short* __restrict__ postb)
{
  const int chunk = blockIdx.x, b = blockIdx.y, side = blockIdx.z;
  const int tid = threadIdx.x, lane = tid & 63, w = tid >> 6;
  const int lr = lane & 15, lg = lane >> 4;
  const int r0 = chunk * 128;

  __shared__ __align__(16) unsigned short seqs[128][72];  // seq rows [r][d]
  __shared__ __align__(16) unsigned short wgt[128][72];   // Wr or Wp [k][d]
  __shared__ __align__(16) unsigned short wlt[64][72];    // Wl^T [i][d]

  const float* seq = (side == 0) ? review : post;
#pragma unroll
  for (int jj = 0; jj < 8; ++jj) {
    int e = tid + jj * 256;            // r = e>>4, d4 = (e&15)*4
    int r = e >> 4, d4 = (e & 15) * 4;
    float4 v = *(const float4*)(seq + ((size_t)(b * 1024 + r0 + r)) * 64 + d4);
    unsigned lo = ((unsigned)f2b(v.y) << 16) | f2b(v.x);
    unsigned hi = ((unsigned)f2b(v.w) << 16) | f2b(v.z);
    *(uint2*)&seqs[r][d4] = make_uint2(lo, hi);
    if (side == 1)
      *(uint2*)(postb + ((size_t)(b * 1024 + r0 + r)) * 64 + d4) = make_uint2(lo, hi);
  }
  const float* wkd = (side == 0) ? Wr : Wp;
#pragma unroll
  for (int jj = 0; jj < 8; ++jj) {
    int e = tid + jj * 256;
    int k = e >> 4, d4 = (e & 15) * 4;
    float4 v = *(const float4*)(wkd + k * 64 + d4);
    unsigned lo = ((unsigned)f2b(v.y) << 16) | f2b(v.x);
    unsigned hi = ((unsigned)f2b(v.w) << 16) | f2b(v.z);
    *(uint2*)&wgt[k][d4] = make_uint2(lo, hi);
  }
  if (side == 0) {
    for (int i = tid; i < 64 * 64; i += 256) {
      int d = i >> 6, c = i & 63;
      wlt[c][d] = f2b(Wl[d * 64 + c]);
    }
  }
  __syncthreads();

  if (side == 0) {
    // RW = seqs @ Wl : [128 x 64]; wave w owns t in [32w, 32w+32)
    ffrag acc[2][4] = {};
#pragma unroll
    for (int ks = 0; ks < 2; ++ks)
#pragma unroll
      for (int ts = 0; ts < 2; ++ts) {
        bfrag a = *(const bfrag*)&seqs[w * 32 + ts * 16 + lr][ks * 32 + lg * 8];
#pragma unroll
        for (int is = 0; is < 4; ++is) {
          bfrag bb = *(const bfrag*)&wlt[is * 16 + lr][ks * 32 + lg * 8];
          acc[ts][is] = MFMA(a, bb, acc[ts][is]);
        }
      }
#pragma unroll
    for (int ts = 0; ts < 2; ++ts)
#pragma unroll
      for (int is = 0; is < 4; ++is)
#pragma unroll
        for (int j = 0; j < 4; ++j) {
          int t = r0 + w * 32 + ts * 16 + lg * 4 + j;
          int i2 = is * 16 + lr;
          RWb[((size_t)(b * 1024 + t)) * 64 + i2] = f2b(acc[ts][is][j]);
        }
  }
  {
    // R/P = wgt @ seqs^T : [128 k x 128 t]; wave w owns k in [32w, 32w+32)
    ffrag acc[2][8] = {};
#pragma unroll
    for (int ks = 0; ks < 2; ++ks)
#pragma unroll
      for (int ksb = 0; ksb < 2; ++ksb) {
        bfrag a = *(const bfrag*)&wgt[w * 32 + ksb * 16 + lr][ks * 32 + lg * 8];
#pragma unroll
        for (int ts = 0; ts < 8; ++ts) {
          bfrag bb = *(const bfrag*)&seqs[ts * 16 + lr][ks * 32 + lg * 8];
          acc[ksb][ts] = MFMA(a, bb, acc[ksb][ts]);
        }
      }
    // fragged store: tc = chunk*4 + (ts2>>1); ts = ts2&1; g = lr>>2; e = lr&3
    //                kt = w*2 + ksb; row lr' = lg*4+j -> lr'*8
    char* dstb = (char*)((side == 0) ? Rb : Pb) + (size_t)b * 262144
                 + (size_t)chunk * 4 * 8192;
#pragma unroll
    for (int ksb = 0; ksb < 2; ++ksb)
#pragma unroll
      for (int ts2 = 0; ts2 < 8; ++ts2) {
        char* base = dstb + (ts2 >> 1) * 8192 + (ts2 & 1) * 4096
                     + (w * 2 + ksb) * 512 + (lr >> 2) * 128 + (lr & 3) * 2;
#pragma unroll
        for (int j = 0; j < 4; ++j)
          *(unsigned short*)(base + (lg * 4 + j) * 8) = f2b(acc[ksb][ts2][j]);
      }
  }
}

// ---------------------------------------------------------------------------
// hz (fused hp+hr), v8 = v7 structure with register pressure fixed:
//  - resident B-frags in LDS (re-read per iter; barrier blocks LICM)
//  - no loop unroll (single live-range set)
//  - non-volatile mfma16 asm
// LDS (40960 B, 4 blocks/CU):
//   rs  @0      [128 rows][128B] XOR-swizzled resident strip
//   rw  @16384  (+4096 dbuf) [32 rows][128B] chunk (pre-swz global src)
//   rl  @24576  (+8192 dbuf) fragged coeff (LINEAR gload)
// Per iter: stage(tc+1) async; 4 b128 resident reads; L(tc): 4 b128 chunk
// reads + 8 MFMA K=32 + tanh -> pk regs; GEMM(tc): 16 b64 reads + 32 MFMA
// K=16 feeding A from pk regs; ONE __syncthreads.
// ---------------------------------------------------------------------------
__global__ __launch_bounds__(256, 4) void hz_kernel(
    const unsigned short* __restrict__ RWb, const unsigned short* __restrict__ Rb,
    const unsigned short* __restrict__ Pb, const unsigned short* __restrict__ postb,
    const float* __restrict__ whp, const float* __restrict__ whr,
    float* __restrict__ zp, float* __restrict__ zr)
{
  const int orig = blockIdx.x;
  const int swz = (orig & 7) * 128 + (orig >> 3);   // XCD-chunked, bijective
  const int strip = swz & 7, pair = swz >> 3;
  const int b = pair & 63, role = pair >> 6;
  const int s0 = strip * 128;
  const int tid = threadIdx.x, lane = tid & 63, w = tid >> 6;
  const int lr = lane & 15, lg = lane >> 4;

  const unsigned short* resident = role ? RWb : postb;
  const unsigned short* chunkseq = role ? postb : RWb;
  const unsigned short* coeff    = role ? Pb : Rb;
  const unsigned short* addterm  = role ? Rb : Pb;
  const float* wh                = role ? whr : whp;
  float* zout                    = role ? zr : zp;

  __shared__ __align__(16) char smem[40960];
  const int woff = w << 10;   // wave-uniform LDS staging base offset

  // chunk staging source (pre-swizzled so linear dest is XOR-swizzled)
  const int crow = tid >> 3, cslot = tid & 7;
  const char* csrc = (const char*)chunkseq + (size_t)b * 131072
                     + crow * 128 + ((cslot ^ (crow & 7)) << 4);   // + tc*4096
  // coeff staging source: fragged layout == LDS layout -> pure linear
  const char* ksrc = (const char*)coeff + (size_t)b * 262144 + tid * 16; // + tc*8192
  // resident staging source (pre-swizzled rows)
  const char* rbase = (const char*)resident + ((size_t)(b * 1024 + s0)) * 128;

  // ---- prologue: resident strip + chunk(0) + coeff(0) ----
#pragma unroll
  for (int q = 0; q < 4; ++q) {
    const int row = q * 32 + (tid >> 3), slot = tid & 7;
    gload16(rbase + row * 128 + ((slot ^ (row & 7)) << 4), smem + q * 4096 + woff);
  }
  gload16(csrc, smem + 16384 + woff);
  gload16(ksrc, smem + 24576 + woff);
  gload16(ksrc + 4096, smem + 24576 + 4096 + woff);
  __syncthreads();

  ffrag acc[2][8] = {};   // [rs][kt]: res strip private to wave, all 128 k

#pragma unroll 1
  for (int tc = 0; tc < 32; ++tc) {
    const int cur = tc & 1, nb = cur ^ 1;
    // ---- issue async staging for tc+1 ----
    if (tc < 31) {
      gload16(csrc + (size_t)(tc + 1) * 4096, smem + 16384 + nb * 4096 + woff);
      gload16(ksrc + (size_t)(tc + 1) * 8192, smem + 24576 + nb * 8192 + woff);
      gload16(ksrc + (size_t)(tc + 1) * 8192 + 4096,
              smem + 24576 + nb * 8192 + 4096 + woff);
    }

    // ---- resident B-frags from LDS (barrier in loop blocks hoisting) ----
    bfrag rb[2][2];
#pragma unroll
    for (int ks = 0; ks < 2; ++ks)
#pragma unroll
      for (int rs = 0; rs < 2; ++rs) {
        const int brow = w * 32 + rs * 16 + lr;
        rb[ks][rs] = *(const bfrag*)(smem + brow * 128 + (((ks * 4 + lg) ^ (brow & 7)) << 4));
      }

    // ---- L-phase(tc): Ltile[chk][res], tanh -> pk regs ----
    const char* rwc = smem + 16384 + cur * 4096;
    uint2 pk[2][2];   // [ts][rs]; == A-frags of the K=16 GEMM
#pragma unroll
    for (int ts = 0; ts < 2; ++ts) {
      ffrag la[2] = {};
#pragma unroll
      for (int ks = 0; ks < 2; ++ks) {
        const int arow = ts * 16 + lr;
        bfrag a = *(const bfrag*)(rwc + arow * 128 + (((ks * 4 + lg) ^ (arow & 7)) << 4));
        la[0] = MFMA(a, rb[ks][0], la[0]);
        la[1] = MFMA(a, rb[ks][1], la[1]);
      }
      pk[ts][0].x = cvtpk(ftanh(la[0][0]), ftanh(la[0][1]));
      pk[ts][0].y = cvtpk(ftanh(la[0][2]), ftanh(la[0][3]));
      pk[ts][1].x = cvtpk(ftanh(la[1][0]), ftanh(la[1][1]));
      pk[ts][1].y = cvtpk(ftanh(la[1][2]), ftanh(la[1][3]));
    }

    // ---- GEMM(tc): acc[res][k] += L^T x coeff (K=16 x2), A from pk regs ----
    const char* rlc = smem + 24576 + cur * 8192;
#pragma unroll
    for (int kt = 0; kt < 8; ++kt) {
#pragma unroll
      for (int ts = 0; ts < 2; ++ts) {
        bfrag4 bk = *(const bfrag4*)(rlc + ts * 4096 + kt * 512 + lg * 128 + lr * 8);
        mfma16(__builtin_bit_cast(bfrag4, pk[ts][0]), bk, acc[0][kt]);
        mfma16(__builtin_bit_cast(bfrag4, pk[ts][1]), bk, acc[1][kt]);
      }
    }
    __syncthreads();   // staging drained + buffers retired
  }

  // ---- epilogue: z[res] = sum_k wh[k] * tanh(acc + addterm) ----
  // lane holds acc for k = kt*16 + lr, res = w*32 + rs*16 + lg*4 + j
  float whs[8];
#pragma unroll
  for (int kt = 0; kt < 8; ++kt) whs[kt] = wh[kt * 16 + lr];

  const char* abase = (const char*)addterm + (size_t)b * 262144
                      + (size_t)(strip * 4 + w) * 8192 + lg * 128 + lr * 8;
  float zsum[2][4] = {};
#pragma unroll
  for (int rs = 0; rs < 2; ++rs)
#pragma unroll
    for (int kt = 0; kt < 8; ++kt) {
      uint2 av = *(const uint2*)(abase + rs * 4096 + kt * 512);
      const float whk = whs[kt];
      zsum[rs][0] += whk * ftanh(acc[rs][kt][0] + b2f((unsigned short)(av.x & 0xFFFF)));
      zsum[rs][1] += whk * ftanh(acc[rs][kt][1] + b2f((unsigned short)(av.x >> 16)));
      zsum[rs][2] += whk * ftanh(acc[rs][kt][2] + b2f((unsigned short)(av.y & 0xFFFF)));
      zsum[rs][3] += whk * ftanh(acc[rs][kt][3] + b2f((unsigned short)(av.y >> 16)));
    }
#pragma unroll
  for (int rs = 0; rs < 2; ++rs)
#pragma unroll
    for (int j = 0; j < 4; ++j) {
      float v = zsum[rs][j];
      v += __shfl_xor(v, 1);
      v += __shfl_xor(v, 2);
      v += __shfl_xor(v, 4);
      v += __shfl_xor(v, 8);
      if (lr == 0)
        zout[(size_t)b * 1024 + s0 + w * 32 + rs * 16 + lg * 4 + j] = v;
    }
}

// ---------------------------------------------------------------------------
// final: block (b, side), 1024 threads: softmax(z) -> weighted seq sum -> out
// ---------------------------------------------------------------------------
__global__ __launch_bounds__(1024) void final_kernel(
    const float* __restrict__ review, const float* __restrict__ post,
    const float* __restrict__ zp, const float* __restrict__ zr,
    float* __restrict__ out)
{
  const int b = blockIdx.x, side = blockIdx.y, tid = threadIdx.x;
  const int wid = tid >> 6, lane = tid & 63;
  __shared__ float zl[1024];
  __shared__ float red[16];
  __shared__ float cacc[16][64];

  const float* z = (side == 0) ? zp : zr;
  const float* seq = (side == 0) ? post : review;

  float v = z[(size_t)b * 1024 + tid];
  zl[tid] = v;
  float m = v;
#pragma unroll
  for (int off = 32; off; off >>= 1) m = fmaxf(m, __shfl_xor(m, off));
  if (lane == 0) red[wid] = m;
  __syncthreads();
  m = red[0];
#pragma unroll
  for (int i = 1; i < 16; ++i) m = fmaxf(m, red[i]);
  __syncthreads();

  float e = __expf(v - m);
  zl[tid] = e;
  float sm = e;
#pragma unroll
  for (int off = 32; off; off >>= 1) sm += __shfl_xor(sm, off);
  if (lane == 0) red[wid] = sm;
  __syncthreads();
  sm = red[0];
#pragma unroll
  for (int i = 1; i < 16; ++i) sm += red[i];
  const float inv = 1.0f / sm;

  const int d = lane;
  float a = 0.f;
  for (int n = wid * 64; n < wid * 64 + 64; ++n)
    a += zl[n] * seq[((size_t)(b * 1024 + n)) * 64 + d];
  cacc[wid][d] = a;
  __syncthreads();
  if (tid < 64) {
    float s = 0.f;
#pragma unroll
    for (int g = 0; g < 16; ++g) s += cacc[g][tid];
    out[b * 128 + side * 64 + tid] = s * inv;
  }
}

// ---------------------------------------------------------------------------
extern "C" void kernel_launch(void* const* d_in, const int* in_sizes, int n_in,
                              void* d_out, int out_size, void* d_ws, size_t ws_size,
                              hipStream_t stream) {
  const float* review = (const float*)d_in[0];
  const float* post   = (const float*)d_in[1];
  const float* Wl     = (const float*)d_in[2];
  const float* Wr     = (const float*)d_in[3];
  const float* Wp     = (const float*)d_in[4];
  const float* whr    = (const float*)d_in[5];
  const float* whp    = (const float*)d_in[6];
  float* out = (float*)d_out;

  char* ws = (char*)d_ws;
  unsigned short* RWb   = (unsigned short*)(ws);                        //  8 MiB
  unsigned short* Rb    = (unsigned short*)(ws + (size_t)8  * 1048576); // 16 MiB
  unsigned short* Pb    = (unsigned short*)(ws + (size_t)24 * 1048576); // 16 MiB
  unsigned short* postb = (unsigned short*)(ws + (size_t)40 * 1048576); //  8 MiB
  float* zp = (float*)(ws + (size_t)48 * 1048576);                      // 256 KiB
  float* zr = (float*)(ws + (size_t)48 * 1048576 + 262144);             // 256 KiB

  prep_kernel<<<dim3(8, 64, 2), dim3(256), 0, stream>>>(
      review, post, Wl, Wr, Wp, RWb, Rb, Pb, postb);
  hz_kernel<<<dim3(1024), dim3(256), 0, stream>>>(
      RWb, Rb, Pb, postb, whp, whr, zp, zr);
  final_kernel<<<dim3(64, 2), dim3(1024), 0, stream>>>(
      review, post, zp, zr, out);
}

// Round 9
// 121.969 us; speedup vs baseline: 1.5143x; 1.1512x over previous
//
#include <hip/hip_runtime.h>
#include <hip/hip_bf16.h>

// Problem constants: B=64, T=N=1024, d=64, k=128.

typedef __attribute__((ext_vector_type(8))) short bfrag;   // 8 x bf16 (4 VGPRs)
typedef __attribute__((ext_vector_type(4))) float ffrag;   // 4 x f32 acc

typedef const __attribute__((address_space(1))) unsigned GAS_U;
typedef __attribute__((address_space(3))) unsigned LAS_U;

__device__ __forceinline__ void gload16(const void* g, void* l) {
  // async global->LDS, 16B per lane; LDS dest = wave-uniform base + lane*16
  __builtin_amdgcn_global_load_lds((GAS_U*)g, (LAS_U*)l, 16, 0, 0);
}

__device__ __forceinline__ unsigned short f2b(float f) {
  unsigned u = __builtin_bit_cast(unsigned, f);
  u += 0x7FFFu + ((u >> 16) & 1u);          // RNE f32 -> bf16 (finite inputs)
  return (unsigned short)(u >> 16);
}
__device__ __forceinline__ float b2f(unsigned short h) {
  return __builtin_bit_cast(float, (unsigned)h << 16);
}
__device__ __forceinline__ float ftanh(float x) {
  // tanh(x) = 1 - 2/(2^(x*2*log2e)+1); ~1e-6 abs err
  float e = __builtin_amdgcn_exp2f(x * 2.88539008177792681f);
  return fmaf(-2.0f, __builtin_amdgcn_rcpf(e + 1.0f), 1.0f);
}
// packed bf16 pair {lo in low16, hi in high16}, RNE, single instruction
__device__ __forceinline__ unsigned cvtpk(float lo, float hi) {
  unsigned r;
  asm("v_cvt_pk_bf16_f32 %0, %1, %2" : "=v"(r) : "v"(lo), "v"(hi));
  return r;
}

#define MFMA(a, b, c) __builtin_amdgcn_mfma_f32_16x16x32_bf16((a), (b), (c), 0, 0, 0)

// ---------------------------------------------------------------------------
// prep (r6 version): RWb = bf16(review@Wl)  [B,T,64]
//       Rb  = bf16(Wr@review^T) row-major [B,128,T]
//       Pb  = bf16(Wp@post^T)   row-major [B,128,N]
//       postb = bf16(post)      [B,N,64]
// ---------------------------------------------------------------------------
__global__ __launch_bounds__(256) void prep_kernel(
    const float* __restrict__ review, const float* __restrict__ post,
    const float* __restrict__ Wl, const float* __restrict__ Wr,
    const float* __restrict__ Wp,
    unsigned short* __restrict__ RWb, unsigned short* __restrict__ Rb,
    unsigned short* __restrict__ Pb, unsigned short* __restrict__ postb)
{
  const int chunk = blockIdx.x, b = blockIdx.y, side = blockIdx.z;
  const int tid = threadIdx.x, lane = tid & 63, w = tid >> 6;
  const int lr = lane & 15, lg = lane >> 4;
  const int r0 = chunk * 128;

  __shared__ __align__(16) unsigned short seqs[128][72];  // seq rows [r][d]
  __shared__ __align__(16) unsigned short wgt[128][72];   // Wr or Wp [k][d]
  __shared__ __align__(16) unsigned short wlt[64][72];    // Wl^T [i][d]

  const float* seq = (side == 0) ? review : post;
#pragma unroll
  for (int jj = 0; jj < 8; ++jj) {
    int e = tid + jj * 256;            // r = e>>4, d4 = (e&15)*4
    int r = e >> 4, d4 = (e & 15) * 4;
    float4 v = *(const float4*)(seq + ((size_t)(b * 1024 + r0 + r)) * 64 + d4);
    unsigned lo = ((unsigned)f2b(v.y) << 16) | f2b(v.x);
    unsigned hi = ((unsigned)f2b(v.w) << 16) | f2b(v.z);
    *(uint2*)&seqs[r][d4] = make_uint2(lo, hi);
    if (side == 1)
      *(uint2*)(postb + ((size_t)(b * 1024 + r0 + r)) * 64 + d4) = make_uint2(lo, hi);
  }
  const float* wkd = (side == 0) ? Wr : Wp;
#pragma unroll
  for (int jj = 0; jj < 8; ++jj) {
    int e = tid + jj * 256;
    int k = e >> 4, d4 = (e & 15) * 4;
    float4 v = *(const float4*)(wkd + k * 64 + d4);
    unsigned lo = ((unsigned)f2b(v.y) << 16) | f2b(v.x);
    unsigned hi = ((unsigned)f2b(v.w) << 16) | f2b(v.z);
    *(uint2*)&wgt[k][d4] = make_uint2(lo, hi);
  }
  if (side == 0) {
    for (int i = tid; i < 64 * 64; i += 256) {
      int d = i >> 6, c = i & 63;
      wlt[c][d] = f2b(Wl[d * 64 + c]);
    }
  }
  __syncthreads();

  if (side == 0) {
    // RW = seqs @ Wl : [128 x 64]; wave w owns t in [32w, 32w+32)
    ffrag acc[2][4] = {};
#pragma unroll
    for (int ks = 0; ks < 2; ++ks)
#pragma unroll
      for (int ts = 0; ts < 2; ++ts) {
        bfrag a = *(const bfrag*)&seqs[w * 32 + ts * 16 + lr][ks * 32 + lg * 8];
#pragma unroll
        for (int is = 0; is < 4; ++is) {
          bfrag bb = *(const bfrag*)&wlt[is * 16 + lr][ks * 32 + lg * 8];
          acc[ts][is] = MFMA(a, bb, acc[ts][is]);
        }
      }
#pragma unroll
    for (int ts = 0; ts < 2; ++ts)
#pragma unroll
      for (int is = 0; is < 4; ++is)
#pragma unroll
        for (int j = 0; j < 4; ++j) {
          int t = r0 + w * 32 + ts * 16 + lg * 4 + j;
          int i2 = is * 16 + lr;
          RWb[((size_t)(b * 1024 + t)) * 64 + i2] = f2b(acc[ts][is][j]);
        }
  }
  {
    // R/P = wgt @ seqs^T : [128 k x 128 r]; wave w owns k in [32w, 32w+32)
    ffrag acc[2][8] = {};
#pragma unroll
    for (int ks = 0; ks < 2; ++ks)
#pragma unroll
      for (int ksb = 0; ksb < 2; ++ksb) {
        bfrag a = *(const bfrag*)&wgt[w * 32 + ksb * 16 + lr][ks * 32 + lg * 8];
#pragma unroll
        for (int ts = 0; ts < 8; ++ts) {
          bfrag bb = *(const bfrag*)&seqs[ts * 16 + lr][ks * 32 + lg * 8];
          acc[ksb][ts] = MFMA(a, bb, acc[ksb][ts]);
        }
      }
    unsigned short* dst = (side == 0) ? Rb : Pb;
#pragma unroll
    for (int ksb = 0; ksb < 2; ++ksb)
#pragma unroll
      for (int ts = 0; ts < 8; ++ts)
#pragma unroll
        for (int j = 0; j < 4; ++j) {
          int k = w * 32 + ksb * 16 + lg * 4 + j;
          int t = r0 + ts * 16 + lr;
          dst[((size_t)(b * 128 + k)) * 1024 + t] = f2b(acc[ksb][ts][j]);
        }
  }
}

// ---------------------------------------------------------------------------
// hz v9: 512-thread blocks (8 waves), 64-row res strips, grid 2048.
// Small per-wave state -> acc[4] = 16 regs; target <=85 regs for occupancy.
//   role 0: z_p (resident=post strip, chunk over t, coeff=R, add=P)
//   role 1: z_r (resident=RW strip, chunk over n, coeff=P, add=R)
// Wave split: L-phase: wave w owns D tile (chk ts=w>>2, res rs=w&3);
//             GEMM: wave w owns k-16 tile (k = w*16+lr), res all 64.
// LDS (28672 B): rw dbuf @0/@4096 [32 rows][128B] chunk (pre-swz global src)
//                rl dbuf @8192/@16384 [4 part][128 k][16B] coeff (scatter src)
//                ll @24576 [4 slot][64 res][16B] frag-major L (zacc alias)
// Per iter: stage(tc+1) async; L: 2 b128 reads + 2 MFMA + 4 tanh -> ll;
// B2; GEMM: 1+4 b128 reads + 4 MFMA; B3.
// ---------------------------------------------------------------------------
__global__ __launch_bounds__(512, 6) void hz_kernel(
    const unsigned short* __restrict__ RWb, const unsigned short* __restrict__ Rb,
    const unsigned short* __restrict__ Pb, const unsigned short* __restrict__ postb,
    const float* __restrict__ whp, const float* __restrict__ whr,
    float* __restrict__ zp, float* __restrict__ zr)
{
  const int orig = blockIdx.x;
  const int swz = (orig & 7) * 256 + (orig >> 3);   // XCD-chunked, bijective
  const int strip = swz & 15, pair = swz >> 4;
  const int b = pair & 63, role = pair >> 6;
  const int s0 = strip * 64;
  const int tid = threadIdx.x, lane = tid & 63, w = tid >> 6;
  const int lr = lane & 15, lg = lane >> 4;

  const unsigned short* resident = role ? RWb : postb;
  const unsigned short* chunkseq = role ? postb : RWb;
  const unsigned short* coeff    = role ? Pb : Rb;
  const unsigned short* addterm  = role ? Rb : Pb;
  const float* wh                = role ? whr : whp;
  float* zout                    = role ? zr : zp;

  __shared__ __align__(16) char smem[28672];
  char* ll = smem + 24576;               // [slot][64 res][16B]
  float* zacc = (float*)(smem + 24576);  // alias ll (post-loop only)

  // ---- staging sources ----
  // chunk (waves 0-3): dest flat = w*1024+lane*16 -> row = w*8+(lane>>3)
  const int crow = (w << 3) + (lane >> 3), cslot = lane & 7;
  const char* csrc = (const char*)chunkseq + (size_t)b * 131072
                     + crow * 128 + ((cslot ^ (crow & 7)) << 4);   // + tc*4096
  // coeff (all 8 waves): dest flat = w*1024+lane*16 -> part = w>>1,
  //   kk = (w&1)*64+lane; src = kk*2048 + part*16 (+ tc*64)
  const int kk = ((w & 1) << 6) + lane;
  const char* ksrc = (const char*)coeff + (size_t)b * 262144
                     + (size_t)kk * 2048 + (w >> 1) * 16;          // + tc*64
  const int woff = w << 10;   // wave-uniform LDS dest offset

  // ---- loop-invariant resident B-frags (8 VGPRs) ----
  const int ts = w >> 2, rs = w & 3;
  bfrag rb[2];
  {
    const char* rbase = (const char*)resident + ((size_t)(b * 1024 + s0)) * 128;
#pragma unroll
    for (int ks = 0; ks < 2; ++ks)
      rb[ks] = *(const bfrag*)(rbase + (rs * 16 + lr) * 128 + ks * 64 + lg * 16);
  }

  // ---- prologue: stage chunk(0) + coeff(0) ----
  if (w < 4) gload16(csrc, smem + woff);
  gload16(ksrc, smem + 8192 + woff);
  __syncthreads();

  ffrag acc[4] = {};   // [nt]: k = w*16+lg*4+j, res = nt*16+lr

#pragma unroll 1
  for (int tc = 0; tc < 32; ++tc) {
    const int cur = tc & 1, nb = cur ^ 1;
    // ---- issue async staging for tc+1 ----
    if (tc < 31) {
      if (w < 4) gload16(csrc + (size_t)(tc + 1) * 4096, smem + nb * 4096 + woff);
      gload16(ksrc + (size_t)(tc + 1) * 64, smem + 8192 + nb * 8192 + woff);
    }

    // ---- L-phase(tc): wave's D tile [chk ts][res rs] ----
    {
      const char* rwc = smem + cur * 4096;
      const int arow = ts * 16 + lr;
      ffrag la = {};
#pragma unroll
      for (int ks = 0; ks < 2; ++ks) {
        bfrag a = *(const bfrag*)(rwc + arow * 128 + (((ks * 4 + lg) ^ (arow & 7)) << 4));
        la = MFMA(a, rb[ks], la);
      }
      uint2 pk;
      pk.x = cvtpk(ftanh(la[0]), ftanh(la[1]));
      pk.y = cvtpk(ftanh(la[2]), ftanh(la[3]));
      // chk = ts*16+lg*4+j -> slot = ts*2+(lg>>1), byte = (lg&1)*8 + j*2
      *(uint2*)(ll + (ts * 2 + (lg >> 1)) * 1024 + (rs * 16 + lr) * 16 + (lg & 1) * 8) = pk;
    }
    __syncthreads();   // B2: ll visible; staging gloads drained

    // ---- GEMM(tc): acc[res] += coeff[k-16] x L (K=32) ----
    {
      const char* rlc = smem + 8192 + cur * 8192;
      bfrag a0 = *(const bfrag*)(rlc + lg * 2048 + (w * 16 + lr) * 16);
#pragma unroll
      for (int nt = 0; nt < 4; ++nt) {
        bfrag bbr = *(const bfrag*)(ll + lg * 1024 + (nt * 16 + lr) * 16);
        acc[nt] = MFMA(a0, bbr, acc[nt]);
      }
    }
    __syncthreads();   // B3: ll/rl[cur] reads retired
  }

  // ---- epilogue: z[res] = sum_k wh[k] * tanh(acc + addterm) ----
  // lane holds acc for k = w*16+lg*4+j, res = nt*16+lr
  const float4 whs4 = *(const float4*)(wh + w * 16 + lg * 4);
  float zpart[4] = {0, 0, 0, 0};
#pragma unroll
  for (int j = 0; j < 4; ++j) {
    const int k = w * 16 + lg * 4 + j;
    const float whk = ((const float*)&whs4)[j];
    const unsigned short* arow = addterm + ((size_t)(b * 128 + k)) * 1024 + s0;
#pragma unroll
    for (int nt = 0; nt < 4; ++nt) {
      const int res = nt * 16 + lr;
      zpart[nt] += whk * ftanh(acc[nt][j] + b2f(arow[res]));
    }
  }
#pragma unroll
  for (int nt = 0; nt < 4; ++nt) {
    zpart[nt] += __shfl_xor(zpart[nt], 16);
    zpart[nt] += __shfl_xor(zpart[nt], 32);
  }
  if (lg == 0) {
#pragma unroll
    for (int nt = 0; nt < 4; ++nt) zacc[w * 64 + nt * 16 + lr] = zpart[nt];
  }
  __syncthreads();
  if (tid < 64) {
    float s = 0.f;
#pragma unroll
    for (int g = 0; g < 8; ++g) s += zacc[g * 64 + tid];
    zout[(size_t)b * 1024 + s0 + tid] = s;
  }
}

// ---------------------------------------------------------------------------
// final: block (b, side), 1024 threads: softmax(z) -> weighted seq sum -> out
// ---------------------------------------------------------------------------
__global__ __launch_bounds__(1024) void final_kernel(
    const float* __restrict__ review, const float* __restrict__ post,
    const float* __restrict__ zp, const float* __restrict__ zr,
    float* __restrict__ out)
{
  const int b = blockIdx.x, side = blockIdx.y, tid = threadIdx.x;
  const int wid = tid >> 6, lane = tid & 63;
  __shared__ float zl[1024];
  __shared__ float red[16];
  __shared__ float cacc[16][64];

  const float* z = (side == 0) ? zp : zr;
  const float* seq = (side == 0) ? post : review;

  float v = z[(size_t)b * 1024 + tid];
  zl[tid] = v;
  float m = v;
#pragma unroll
  for (int off = 32; off; off >>= 1) m = fmaxf(m, __shfl_xor(m, off));
  if (lane == 0) red[wid] = m;
  __syncthreads();
  m = red[0];
#pragma unroll
  for (int i = 1; i < 16; ++i) m = fmaxf(m, red[i]);
  __syncthreads();

  float e = __expf(v - m);
  zl[tid] = e;
  float sm = e;
#pragma unroll
  for (int off = 32; off; off >>= 1) sm += __shfl_xor(sm, off);
  if (lane == 0) red[wid] = sm;
  __syncthreads();
  sm = red[0];
#pragma unroll
  for (int i = 1; i < 16; ++i) sm += red[i];
  const float inv = 1.0f / sm;

  const int d = lane;
  float a = 0.f;
  for (int n = wid * 64; n < wid * 64 + 64; ++n)
    a += zl[n] * seq[((size_t)(b * 1024 + n)) * 64 + d];
  cacc[wid][d] = a;
  __syncthreads();
  if (tid < 64) {
    float s = 0.f;
#pragma unroll
    for (int g = 0; g < 16; ++g) s += cacc[g][tid];
    out[b * 128 + side * 64 + tid] = s * inv;
  }
}

// ---------------------------------------------------------------------------
extern "C" void kernel_launch(void* const* d_in, const int* in_sizes, int n_in,
                              void* d_out, int out_size, void* d_ws, size_t ws_size,
                              hipStream_t stream) {
  const float* review = (const float*)d_in[0];
  const float* post   = (const float*)d_in[1];
  const float* Wl     = (const float*)d_in[2];
  const float* Wr     = (const float*)d_in[3];
  const float* Wp     = (const float*)d_in[4];
  const float* whr    = (const float*)d_in[5];
  const float* whp    = (const float*)d_in[6];
  float* out = (float*)d_out;

  char* ws = (char*)d_ws;
  unsigned short* RWb   = (unsigned short*)(ws);                        //  8 MiB
  unsigned short* Rb    = (unsigned short*)(ws + (size_t)8  * 1048576); // 16 MiB
  unsigned short* Pb    = (unsigned short*)(ws + (size_t)24 * 1048576); // 16 MiB
  unsigned short* postb = (unsigned short*)(ws + (size_t)40 * 1048576); //  8 MiB
  float* zp = (float*)(ws + (size_t)48 * 1048576);                      // 256 KiB
  float* zr = (float*)(ws + (size_t)48 * 1048576 + 262144);             // 256 KiB

  prep_kernel<<<dim3(8, 64, 2), dim3(256), 0, stream>>>(
      review, post, Wl, Wr, Wp, RWb, Rb, Pb, postb);
  hz_kernel<<<dim3(2048), dim3(512), 0, stream>>>(
      RWb, Rb, Pb, postb, whp, whr, zp, zr);
  final_kernel<<<dim3(64, 2), dim3(1024), 0, stream>>>(
      review, post, zp, zr, out);
}

// Round 10
// 119.272 us; speedup vs baseline: 1.5485x; 1.0226x over previous
//
#include <hip/hip_runtime.h>
#include <hip/hip_bf16.h>

// Problem constants: B=64, T=N=1024, d=64, k=128.

typedef __attribute__((ext_vector_type(8))) short bfrag;    // 8 x bf16 (4 VGPRs)
typedef __attribute__((ext_vector_type(4))) short bfrag4;   // 4 x bf16 (2 VGPRs)
typedef __attribute__((ext_vector_type(4))) float ffrag;    // 4 x f32 acc

typedef const __attribute__((address_space(1))) unsigned GAS_U;
typedef __attribute__((address_space(3))) unsigned LAS_U;

__device__ __forceinline__ void gload16(const void* g, void* l) {
  // async global->LDS, 16B per lane; LDS dest = wave-uniform base + lane*16
  __builtin_amdgcn_global_load_lds((GAS_U*)g, (LAS_U*)l, 16, 0, 0);
}

__device__ __forceinline__ unsigned short f2b(float f) {
  unsigned u = __builtin_bit_cast(unsigned, f);
  u += 0x7FFFu + ((u >> 16) & 1u);          // RNE f32 -> bf16 (finite inputs)
  return (unsigned short)(u >> 16);
}
__device__ __forceinline__ float b2f(unsigned short h) {
  return __builtin_bit_cast(float, (unsigned)h << 16);
}
__device__ __forceinline__ float ftanh(float x) {
  // tanh(x) = 1 - 2/(2^(x*2*log2e)+1); ~1e-6 abs err
  float e = __builtin_amdgcn_exp2f(x * 2.88539008177792681f);
  return fmaf(-2.0f, __builtin_amdgcn_rcpf(e + 1.0f), 1.0f);
}
// packed bf16 pair {lo in low16, hi in high16}, RNE, single instruction
__device__ __forceinline__ unsigned cvtpk(float lo, float hi) {
  unsigned r;
  asm("v_cvt_pk_bf16_f32 %0, %1, %2" : "=v"(r) : "v"(lo), "v"(hi));
  return r;
}

#define MFMA(a, b, c) __builtin_amdgcn_mfma_f32_16x16x32_bf16((a), (b), (c), 0, 0, 0)

// K=16 MFMA: D[res16][k16] += A[res16][chk16] * B[chk16][k16]
// A lane layout == 16x16 D layout => A comes straight from the L-phase
// accumulator (packed bf16), zero shuffling. Verified in r7/r8 (absmax pass).
__device__ __forceinline__ void mfma16(bfrag4 a, bfrag4 b, ffrag& c) {
  asm("v_mfma_f32_16x16x16_bf16 %0, %1, %2, %0" : "+a"(c) : "v"(a), "v"(b));
}

// Fragged coeff/addterm global layout (per b, per tc-chunk of 32 cols):
//   element (k, t):  tc=t>>5, chk=t&31, ts=chk>>4, g=(chk>>2)&3, e=chk&3,
//                    kt=k>>4, lr=k&15
//   byte = b*262144 + tc*8192 + ts*4096 + kt*512 + g*128 + lr*8 + e*2
// K=16 B-frag read (lane l, tile (ts,kt)): addr = ts*4096+kt*512+(l>>4)*128
//   +(l&15)*8 -> 512B contiguous per wave read: conflict-free.

// ---------------------------------------------------------------------------
// prep (r8 version, verified): RWb = bf16(review@Wl) [B,T,64]
//   Rb/Pb = bf16(Wr@review^T / Wp@post^T) in FRAGGED layout; postb [B,N,64]
// ---------------------------------------------------------------------------
__global__ __launch_bounds__(256) void prep_kernel(
    const float* __restrict__ review, const float* __restrict__ post,
    const float* __restrict__ Wl, const float* __restrict__ Wr,
    const float* __restrict__ Wp,
    unsigned short* __restrict__ RWb, unsigned short* __restrict__ Rb,
    unsigned short* __restrict__ Pb, unsigned short* __restrict__ postb)
{
  const int chunk = blockIdx.x, b = blockIdx.y, side = blockIdx.z;
  const int tid = threadIdx.x, lane = tid & 63, w = tid >> 6;
  const int lr = lane & 15, lg = lane >> 4;
  const int r0 = chunk * 128;

  __shared__ __align__(16) unsigned short seqs[128][72];  // seq rows [r][d]
  __shared__ __align__(16) unsigned short wgt[128][72];   // Wr or Wp [k][d]
  __shared__ __align__(16) unsigned short wlt[64][72];    // Wl^T [i][d]

  const float* seq = (side == 0) ? review : post;
#pragma unroll
  for (int jj = 0; jj < 8; ++jj) {
    int e = tid + jj * 256;            // r = e>>4, d4 = (e&15)*4
    int r = e >> 4, d4 = (e & 15) * 4;
    float4 v = *(const float4*)(seq + ((size_t)(b * 1024 + r0 + r)) * 64 + d4);
    unsigned lo = ((unsigned)f2b(v.y) << 16) | f2b(v.x);
    unsigned hi = ((unsigned)f2b(v.w) << 16) | f2b(v.z);
    *(uint2*)&seqs[r][d4] = make_uint2(lo, hi);
    if (side == 1)
      *(uint2*)(postb + ((size_t)(b * 1024 + r0 + r)) * 64 + d4) = make_uint2(lo, hi);
  }
  const float* wkd = (side == 0) ? Wr : Wp;
#pragma unroll
  for (int jj = 0; jj < 8; ++jj) {
    int e = tid + jj * 256;
    int k = e >> 4, d4 = (e & 15) * 4;
    float4 v = *(const float4*)(wkd + k * 64 + d4);
    unsigned lo = ((unsigned)f2b(v.y) << 16) | f2b(v.x);
    unsigned hi = ((unsigned)f2b(v.w) << 16) | f2b(v.z);
    *(uint2*)&wgt[k][d4] = make_uint2(lo, hi);
  }
  if (side == 0) {
    for (int i = tid; i < 64 * 64; i += 256) {
      int d = i >> 6, c = i & 63;
      wlt[c][d] = f2b(Wl[d * 64 + c]);
    }
  }
  __syncthreads();

  if (side == 0) {
    // RW = seqs @ Wl : [128 x 64]; wave w owns t in [32w, 32w+32)
    ffrag acc[2][4] = {};
#pragma unroll
    for (int ks = 0; ks < 2; ++ks)
#pragma unroll
      for (int ts = 0; ts < 2; ++ts) {
        bfrag a = *(const bfrag*)&seqs[w * 32 + ts * 16 + lr][ks * 32 + lg * 8];
#pragma unroll
        for (int is = 0; is < 4; ++is) {
          bfrag bb = *(const bfrag*)&wlt[is * 16 + lr][ks * 32 + lg * 8];
          acc[ts][is] = MFMA(a, bb, acc[ts][is]);
        }
      }
#pragma unroll
    for (int ts = 0; ts < 2; ++ts)
#pragma unroll
      for (int is = 0; is < 4; ++is)
#pragma unroll
        for (int j = 0; j < 4; ++j) {
          int t = r0 + w * 32 + ts * 16 + lg * 4 + j;
          int i2 = is * 16 + lr;
          RWb[((size_t)(b * 1024 + t)) * 64 + i2] = f2b(acc[ts][is][j]);
        }
  }
  {
    // R/P = wgt @ seqs^T : [128 k x 128 t]; wave w owns k in [32w, 32w+32)
    ffrag acc[2][8] = {};
#pragma unroll
    for (int ks = 0; ks < 2; ++ks)
#pragma unroll
      for (int ksb = 0; ksb < 2; ++ksb) {
        bfrag a = *(const bfrag*)&wgt[w * 32 + ksb * 16 + lr][ks * 32 + lg * 8];
#pragma unroll
        for (int ts = 0; ts < 8; ++ts) {
          bfrag bb = *(const bfrag*)&seqs[ts * 16 + lr][ks * 32 + lg * 8];
          acc[ksb][ts] = MFMA(a, bb, acc[ksb][ts]);
        }
      }
    // fragged store: tc = chunk*4 + (ts2>>1); ts = ts2&1; g = lr>>2; e = lr&3
    //                kt = w*2 + ksb; row lr' = lg*4+j -> lr'*8
    char* dstb = (char*)((side == 0) ? Rb : Pb) + (size_t)b * 262144
                 + (size_t)chunk * 4 * 8192;
#pragma unroll
    for (int ksb = 0; ksb < 2; ++ksb)
#pragma unroll
      for (int ts2 = 0; ts2 < 8; ++ts2) {
        char* base = dstb + (ts2 >> 1) * 8192 + (ts2 & 1) * 4096
                     + (w * 2 + ksb) * 512 + (lr >> 2) * 128 + (lr & 3) * 2;
#pragma unroll
        for (int j = 0; j < 4; ++j)
          *(unsigned short*)(base + (lg * 4 + j) * 8) = f2b(acc[ksb][ts2][j]);
      }
  }
}

// ---------------------------------------------------------------------------
// hz v10: wave-independent. 512-thread blocks (8 waves), grid 1024.
// Wave w owns res rows [s0+w*16, +16) x ALL 128 k. L-phase result feeds the
// K=16 GEMM directly from registers (no ll buffer, no producer barrier).
//   role 0: z_p (resident=post strip, chunk over t, coeff=R, add=P)
//   role 1: z_r (resident=RW strip, chunk over n, coeff=P, add=R)
// LDS (24576 B): rw dbuf @0/@4096 [32 rows][128B] chunk (pre-swz global src)
//                rl dbuf @8192/@16384 fragged coeff (LINEAR gload src)
// Per iter: stage(tc+1) async; L: 4 b128 reads + 4 MFMA K=32 + 8 tanh ->
// pk regs; GEMM: 16 b64 reads + 16 MFMA K=16 (8 indep chains); ONE barrier.
// Regs: acc 32 (AGPR) + rb 8 + pk 4 + ~40 addr/temp -> ~85 unified, no spill.
// ---------------------------------------------------------------------------
__global__ __launch_bounds__(512, 4) void hz_kernel(
    const unsigned short* __restrict__ RWb, const unsigned short* __restrict__ Rb,
    const unsigned short* __restrict__ Pb, const unsigned short* __restrict__ postb,
    const float* __restrict__ whp, const float* __restrict__ whr,
    float* __restrict__ zp, float* __restrict__ zr)
{
  const int orig = blockIdx.x;
  const int swz = (orig & 7) * 128 + (orig >> 3);   // XCD-chunked, bijective
  const int strip = swz & 7, pair = swz >> 3;
  const int b = pair & 63, role = pair >> 6;
  const int s0 = strip * 128;
  const int tid = threadIdx.x, lane = tid & 63, w = tid >> 6;
  const int lr = lane & 15, lg = lane >> 4;

  const unsigned short* resident = role ? RWb : postb;
  const unsigned short* chunkseq = role ? postb : RWb;
  const unsigned short* coeff    = role ? Pb : Rb;
  const unsigned short* addterm  = role ? Rb : Pb;
  const float* wh                = role ? whr : whp;
  float* zout                    = role ? zr : zp;

  __shared__ __align__(16) char smem[24576];
  const int woff = w << 10;   // wave-uniform LDS staging base offset

  // chunk staging source (pre-swizzled so linear dest is XOR-swizzled);
  // only waves 0-3 issue (4KB per tc)
  const int crow = tid >> 3, cslot = tid & 7;
  const char* csrc = (const char*)chunkseq + (size_t)b * 131072
                     + crow * 128 + ((cslot ^ (crow & 7)) << 4);   // + tc*4096
  // coeff staging source: fragged layout == LDS layout -> pure linear,
  // all 8 waves (8KB per tc)
  const char* ksrc = (const char*)coeff + (size_t)b * 262144 + tid * 16; // + tc*8192

  // ---- loop-invariant resident B-frags (8 VGPRs): rows res = w*16+lr ----
  bfrag rb[2];
  {
    const char* rbase = (const char*)resident + ((size_t)(b * 1024 + s0)) * 128
                        + (w * 16 + lr) * 128 + lg * 16;
    rb[0] = *(const bfrag*)(rbase);
    rb[1] = *(const bfrag*)(rbase + 64);
  }

  // ---- prologue: stage chunk(0) + coeff(0) ----
  if (w < 4) gload16(csrc, smem + woff);
  gload16(ksrc, smem + 8192 + woff);
  __syncthreads();

  ffrag acc[8] = {};   // [kt]: k = kt*16+lr, res = s0 + w*16 + lg*4 + j

#pragma unroll 1
  for (int tc = 0; tc < 32; ++tc) {
    const int cur = tc & 1, nb = cur ^ 1;
    // ---- issue async staging for tc+1 ----
    if (tc < 31) {
      if (w < 4) gload16(csrc + (size_t)(tc + 1) * 4096, smem + nb * 4096 + woff);
      gload16(ksrc + (size_t)(tc + 1) * 8192, smem + 8192 + nb * 8192 + woff);
    }

    // ---- L-phase(tc): D[chk32][res16] -> tanh -> pk regs (K=16 A-frags) ----
    const char* rwc = smem + cur * 4096;
    uint2 pk[2];   // [ts]
#pragma unroll
    for (int ts = 0; ts < 2; ++ts) {
      ffrag la = {};
#pragma unroll
      for (int ks = 0; ks < 2; ++ks) {
        const int arow = ts * 16 + lr;
        bfrag a = *(const bfrag*)(rwc + arow * 128 + (((ks * 4 + lg) ^ (arow & 7)) << 4));
        la = MFMA(a, rb[ks], la);
      }
      pk[ts].x = cvtpk(ftanh(la[0]), ftanh(la[1]));
      pk[ts].y = cvtpk(ftanh(la[2]), ftanh(la[3]));
    }

    // ---- GEMM(tc): acc[kt] += L^T x coeff (K=16 x2), A from pk regs ----
    const char* rlc = smem + 8192 + cur * 8192 + lg * 128 + lr * 8;
#pragma unroll
    for (int kt = 0; kt < 8; ++kt) {
      bfrag4 b0 = *(const bfrag4*)(rlc + kt * 512);
      bfrag4 b1 = *(const bfrag4*)(rlc + 4096 + kt * 512);
      mfma16(__builtin_bit_cast(bfrag4, pk[0]), b0, acc[kt]);
      mfma16(__builtin_bit_cast(bfrag4, pk[1]), b1, acc[kt]);
    }
    __syncthreads();   // staging drained + buffers retired (ONE barrier/iter)
  }

  // ---- epilogue (wave-local): z[res] = sum_k wh[k] * tanh(acc + add) ----
  // lane holds acc[kt][j]: k = kt*16+lr, res = s0 + w*16 + lg*4 + j
  float whs[8];
#pragma unroll
  for (int kt = 0; kt < 8; ++kt) whs[kt] = wh[kt * 16 + lr];

  // addterm fragged read: res -> tc_a = strip*4+(w>>1), ts_a = w&1,
  //                       g_a = lg, e_a = j
  const char* abase = (const char*)addterm + (size_t)b * 262144
                      + (size_t)(strip * 4 + (w >> 1)) * 8192 + (w & 1) * 4096
                      + lg * 128 + lr * 8;
  float zs[4] = {0, 0, 0, 0};
#pragma unroll
  for (int kt = 0; kt < 8; ++kt) {
    uint2 av = *(const uint2*)(abase + kt * 512);
    const float whk = whs[kt];
    zs[0] += whk * ftanh(acc[kt][0] + b2f((unsigned short)(av.x & 0xFFFF)));
    zs[1] += whk * ftanh(acc[kt][1] + b2f((unsigned short)(av.x >> 16)));
    zs[2] += whk * ftanh(acc[kt][2] + b2f((unsigned short)(av.y & 0xFFFF)));
    zs[3] += whk * ftanh(acc[kt][3] + b2f((unsigned short)(av.y >> 16)));
  }
#pragma unroll
  for (int j = 0; j < 4; ++j) {
    zs[j] += __shfl_xor(zs[j], 1);
    zs[j] += __shfl_xor(zs[j], 2);
    zs[j] += __shfl_xor(zs[j], 4);
    zs[j] += __shfl_xor(zs[j], 8);
  }
  if (lr == 0) {
#pragma unroll
    for (int j = 0; j < 4; ++j)
      zout[(size_t)b * 1024 + s0 + w * 16 + lg * 4 + j] = zs[j];
  }
}

// ---------------------------------------------------------------------------
// final: block (b, side), 1024 threads: softmax(z) -> weighted seq sum -> out
// ---------------------------------------------------------------------------
__global__ __launch_bounds__(1024) void final_kernel(
    const float* __restrict__ review, const float* __restrict__ post,
    const float* __restrict__ zp, const float* __restrict__ zr,
    float* __restrict__ out)
{
  const int b = blockIdx.x, side = blockIdx.y, tid = threadIdx.x;
  const int wid = tid >> 6, lane = tid & 63;
  __shared__ float zl[1024];
  __shared__ float red[16];
  __shared__ float cacc[16][64];

  const float* z = (side == 0) ? zp : zr;
  const float* seq = (side == 0) ? post : review;

  float v = z[(size_t)b * 1024 + tid];
  zl[tid] = v;
  float m = v;
#pragma unroll
  for (int off = 32; off; off >>= 1) m = fmaxf(m, __shfl_xor(m, off));
  if (lane == 0) red[wid] = m;
  __syncthreads();
  m = red[0];
#pragma unroll
  for (int i = 1; i < 16; ++i) m = fmaxf(m, red[i]);
  __syncthreads();

  float e = __expf(v - m);
  zl[tid] = e;
  float sm = e;
#pragma unroll
  for (int off = 32; off; off >>= 1) sm += __shfl_xor(sm, off);
  if (lane == 0) red[wid] = sm;
  __syncthreads();
  sm = red[0];
#pragma unroll
  for (int i = 1; i < 16; ++i) sm += red[i];
  const float inv = 1.0f / sm;

  const int d = lane;
  float a = 0.f;
  for (int n = wid * 64; n < wid * 64 + 64; ++n)
    a += zl[n] * seq[((size_t)(b * 1024 + n)) * 64 + d];
  cacc[wid][d] = a;
  __syncthreads();
  if (tid < 64) {
    float s = 0.f;
#pragma unroll
    for (int g = 0; g < 16; ++g) s += cacc[g][tid];
    out[b * 128 + side * 64 + tid] = s * inv;
  }
}

// ---------------------------------------------------------------------------
extern "C" void kernel_launch(void* const* d_in, const int* in_sizes, int n_in,
                              void* d_out, int out_size, void* d_ws, size_t ws_size,
                              hipStream_t stream) {
  const float* review = (const float*)d_in[0];
  const float* post   = (const float*)d_in[1];
  const float* Wl     = (const float*)d_in[2];
  const float* Wr     = (const float*)d_in[3];
  const float* Wp     = (const float*)d_in[4];
  const float* whr    = (const float*)d_in[5];
  const float* whp    = (const float*)d_in[6];
  float* out = (float*)d_out;

  char* ws = (char*)d_ws;
  unsigned short* RWb   = (unsigned short*)(ws);                        //  8 MiB
  unsigned short* Rb    = (unsigned short*)(ws + (size_t)8  * 1048576); // 16 MiB
  unsigned short* Pb    = (unsigned short*)(ws + (size_t)24 * 1048576); // 16 MiB
  unsigned short* postb = (unsigned short*)(ws + (size_t)40 * 1048576); //  8 MiB
  float* zp = (float*)(ws + (size_t)48 * 1048576);                      // 256 KiB
  float* zr = (float*)(ws + (size_t)48 * 1048576 + 262144);             // 256 KiB

  prep_kernel<<<dim3(8, 64, 2), dim3(256), 0, stream>>>(
      review, post, Wl, Wr, Wp, RWb, Rb, Pb, postb);
  hz_kernel<<<dim3(1024), dim3(512), 0, stream>>>(
      RWb, Rb, Pb, postb, whp, whr, zp, zr);
  final_kernel<<<dim3(64, 2), dim3(1024), 0, stream>>>(
      review, post, zp, zr, out);
}

// Round 11
// 116.611 us; speedup vs baseline: 1.5839x; 1.0228x over previous
//
#include <hip/hip_runtime.h>
#include <hip/hip_bf16.h>

// Problem constants: B=64, T=N=1024, d=64, k=128.

typedef __attribute__((ext_vector_type(8))) short bfrag;    // 8 x bf16 (4 VGPRs)
typedef __attribute__((ext_vector_type(4))) float ffrag;    // 4 x f32 acc

typedef const __attribute__((address_space(1))) unsigned GAS_U;
typedef __attribute__((address_space(3))) unsigned LAS_U;

__device__ __forceinline__ void gload16(const void* g, void* l) {
  // async global->LDS, 16B per lane; LDS dest = wave-uniform base + lane*16
  __builtin_amdgcn_global_load_lds((GAS_U*)g, (LAS_U*)l, 16, 0, 0);
}

__device__ __forceinline__ unsigned short f2b(float f) {
  unsigned u = __builtin_bit_cast(unsigned, f);
  u += 0x7FFFu + ((u >> 16) & 1u);          // RNE f32 -> bf16 (finite inputs)
  return (unsigned short)(u >> 16);
}
__device__ __forceinline__ float b2f(unsigned short h) {
  return __builtin_bit_cast(float, (unsigned)h << 16);
}
__device__ __forceinline__ float ftanh(float x) {
  // tanh(x) = 1 - 2/(2^(x*2*log2e)+1); ~1e-6 abs err
  float e = __builtin_amdgcn_exp2f(x * 2.88539008177792681f);
  return fmaf(-2.0f, __builtin_amdgcn_rcpf(e + 1.0f), 1.0f);
}
// packed bf16 pair {lo in low16, hi in high16}, RNE, single instruction
__device__ __forceinline__ unsigned cvtpk(float lo, float hi) {
  unsigned r;
  asm("v_cvt_pk_bf16_f32 %0, %1, %2" : "=v"(r) : "v"(lo), "v"(hi));
  return r;
}

#define MFMA(a, b, c) __builtin_amdgcn_mfma_f32_16x16x32_bf16((a), (b), (c), 0, 0, 0)

// Fragged coeff/addterm layout (K=32 slot-matched to the L-phase D-tiles):
//   element (k, t): tc=t>>5; c=t&31; ts'=c>>4; g=(c>>2)&3; j_c=c&3;
//                   e = ts'*4 + j_c; kt=k>>4; lr_k=k&15
//   byte = b*262144 + tc*8192 + kt*1024 + g*256 + lr_k*16 + e*2
// The K=32 A operand in hz is {pk[0].x,pk[0].y,pk[1].x,pk[1].y} whose slot
// (g, e=ts*4+j) holds chk = ts*16+g*4+j — the SAME (g,e)->chk map as above,
// so the contraction pairs correctly (operand slot pairing is symmetric;
// HW-validated by the K=16 variant passing absmax in r7/r8/r10).
// B-frag read (lane l, tile kt): addr = kt*1024 + (l>>4)*256 + (l&15)*16
//   -> 1024B contiguous per wave: conflict-free ds_read_b128.

// ---------------------------------------------------------------------------
// prep: RWb = bf16(review@Wl) [B,T,64]
//   Rb/Pb = bf16(Wr@review^T / Wp@post^T) in FRAGGED layout; postb [B,N,64]
// ---------------------------------------------------------------------------
__global__ __launch_bounds__(256) void prep_kernel(
    const float* __restrict__ review, const float* __restrict__ post,
    const float* __restrict__ Wl, const float* __restrict__ Wr,
    const float* __restrict__ Wp,
    unsigned short* __restrict__ RWb, unsigned short* __restrict__ Rb,
    unsigned short* __restrict__ Pb, unsigned short* __restrict__ postb)
{
  const int chunk = blockIdx.x, b = blockIdx.y, side = blockIdx.z;
  const int tid = threadIdx.x, lane = tid & 63, w = tid >> 6;
  const int lr = lane & 15, lg = lane >> 4;
  const int r0 = chunk * 128;

  __shared__ __align__(16) unsigned short seqs[128][72];  // seq rows [r][d]
  __shared__ __align__(16) unsigned short wgt[128][72];   // Wr or Wp [k][d]
  __shared__ __align__(16) unsigned short wlt[64][72];    // Wl^T [i][d]

  const float* seq = (side == 0) ? review : post;
#pragma unroll
  for (int jj = 0; jj < 8; ++jj) {
    int e = tid + jj * 256;            // r = e>>4, d4 = (e&15)*4
    int r = e >> 4, d4 = (e & 15) * 4;
    float4 v = *(const float4*)(seq + ((size_t)(b * 1024 + r0 + r)) * 64 + d4);
    unsigned lo = ((unsigned)f2b(v.y) << 16) | f2b(v.x);
    unsigned hi = ((unsigned)f2b(v.w) << 16) | f2b(v.z);
    *(uint2*)&seqs[r][d4] = make_uint2(lo, hi);
    if (side == 1)
      *(uint2*)(postb + ((size_t)(b * 1024 + r0 + r)) * 64 + d4) = make_uint2(lo, hi);
  }
  const float* wkd = (side == 0) ? Wr : Wp;
#pragma unroll
  for (int jj = 0; jj < 8; ++jj) {
    int e = tid + jj * 256;
    int k = e >> 4, d4 = (e & 15) * 4;
    float4 v = *(const float4*)(wkd + k * 64 + d4);
    unsigned lo = ((unsigned)f2b(v.y) << 16) | f2b(v.x);
    unsigned hi = ((unsigned)f2b(v.w) << 16) | f2b(v.z);
    *(uint2*)&wgt[k][d4] = make_uint2(lo, hi);
  }
  if (side == 0) {
    for (int i = tid; i < 64 * 64; i += 256) {
      int d = i >> 6, c = i & 63;
      wlt[c][d] = f2b(Wl[d * 64 + c]);
    }
  }
  __syncthreads();

  if (side == 0) {
    // RW = seqs @ Wl : [128 x 64]; wave w owns t in [32w, 32w+32)
    ffrag acc[2][4] = {};
#pragma unroll
    for (int ks = 0; ks < 2; ++ks)
#pragma unroll
      for (int ts = 0; ts < 2; ++ts) {
        bfrag a = *(const bfrag*)&seqs[w * 32 + ts * 16 + lr][ks * 32 + lg * 8];
#pragma unroll
        for (int is = 0; is < 4; ++is) {
          bfrag bb = *(const bfrag*)&wlt[is * 16 + lr][ks * 32 + lg * 8];
          acc[ts][is] = MFMA(a, bb, acc[ts][is]);
        }
      }
#pragma unroll
    for (int ts = 0; ts < 2; ++ts)
#pragma unroll
      for (int is = 0; is < 4; ++is)
#pragma unroll
        for (int j = 0; j < 4; ++j) {
          int t = r0 + w * 32 + ts * 16 + lg * 4 + j;
          int i2 = is * 16 + lr;
          RWb[((size_t)(b * 1024 + t)) * 64 + i2] = f2b(acc[ts][is][j]);
        }
  }
  {
    // R/P = wgt @ seqs^T : [128 k x 128 t]; wave w owns k in [32w, 32w+32)
    // D element: k = w*32+ksb*16+lg*4+j, t = r0 + ts2*16 + lr
    ffrag acc[2][8] = {};
#pragma unroll
    for (int ks = 0; ks < 2; ++ks)
#pragma unroll
      for (int ksb = 0; ksb < 2; ++ksb) {
        bfrag a = *(const bfrag*)&wgt[w * 32 + ksb * 16 + lr][ks * 32 + lg * 8];
#pragma unroll
        for (int ts = 0; ts < 8; ++ts) {
          bfrag bb = *(const bfrag*)&seqs[ts * 16 + lr][ks * 32 + lg * 8];
          acc[ksb][ts] = MFMA(a, bb, acc[ksb][ts]);
        }
      }
    // fragged store per layout comment:
    //   tc = chunk*4 + (ts2>>1); c = (ts2&1)*16 + lr -> ts' = ts2&1,
    //   g = lr>>2, j_c = lr&3, e = (ts2&1)*4 + (lr&3)
    //   kt = w*2 + ksb; lr_k = lg*4 + j
    char* dstb = (char*)((side == 0) ? Rb : Pb) + (size_t)b * 262144
                 + (size_t)chunk * 4 * 8192;
#pragma unroll
    for (int ksb = 0; ksb < 2; ++ksb)
#pragma unroll
      for (int ts2 = 0; ts2 < 8; ++ts2) {
        char* base = dstb + (ts2 >> 1) * 8192 + (w * 2 + ksb) * 1024
                     + (lr >> 2) * 256 + ((ts2 & 1) * 4 + (lr & 3)) * 2;
#pragma unroll
        for (int j = 0; j < 4; ++j)
          *(unsigned short*)(base + (lg * 4 + j) * 16) = f2b(acc[ksb][ts2][j]);
      }
  }
}

// ---------------------------------------------------------------------------
// hz v11: wave-independent (r10 structure) + FULL-RATE K=32 GEMM whose A
// operand is the concatenated L-phase D-tiles (slot-matched coeff layout).
// 512-thread blocks (8 waves), grid 1024; wave w owns res rows
// [s0+w*16,+16) x all 128 k. ONE barrier/iter, no L round-trip.
// LDS (24576 B): rw dbuf @0/@4096 [32 rows][128B] chunk (pre-swz global src)
//                rl dbuf @8192/@16384 fragged coeff (LINEAR gload src)
// Per iter: stage(tc+1) async; L: 4 b128 + 4 MFMA K=32 + 8 tanh -> pk;
// GEMM: 8 b128 + 8 MFMA K=32 (indep chains); barrier.
// ---------------------------------------------------------------------------
__global__ __launch_bounds__(512, 4) void hz_kernel(
    const unsigned short* __restrict__ RWb, const unsigned short* __restrict__ Rb,
    const unsigned short* __restrict__ Pb, const unsigned short* __restrict__ postb,
    const float* __restrict__ whp, const float* __restrict__ whr,
    float* __restrict__ zp, float* __restrict__ zr)
{
  const int orig = blockIdx.x;
  const int swz = (orig & 7) * 128 + (orig >> 3);   // XCD-chunked, bijective
  const int strip = swz & 7, pair = swz >> 3;
  const int b = pair & 63, role = pair >> 6;
  const int s0 = strip * 128;
  const int tid = threadIdx.x, lane = tid & 63, w = tid >> 6;
  const int lr = lane & 15, lg = lane >> 4;

  const unsigned short* resident = role ? RWb : postb;
  const unsigned short* chunkseq = role ? postb : RWb;
  const unsigned short* coeff    = role ? Pb : Rb;
  const unsigned short* addterm  = role ? Rb : Pb;
  const float* wh                = role ? whr : whp;
  float* zout                    = role ? zr : zp;

  __shared__ __align__(16) char smem[24576];
  const int woff = w << 10;   // wave-uniform LDS staging base offset

  // chunk staging source (pre-swizzled so linear dest is XOR-swizzled);
  // waves 0-3 issue (4KB per tc)
  const int crow = tid >> 3, cslot = tid & 7;
  const char* csrc = (const char*)chunkseq + (size_t)b * 131072
                     + crow * 128 + ((cslot ^ (crow & 7)) << 4);   // + tc*4096
  // coeff staging source: fragged layout == LDS layout -> pure linear,
  // all 8 waves (8KB per tc)
  const char* ksrc = (const char*)coeff + (size_t)b * 262144 + tid * 16; // + tc*8192

  // ---- loop-invariant resident B-frags (8 VGPRs): rows res = w*16+lr ----
  bfrag rb[2];
  {
    const char* rbase = (const char*)resident + ((size_t)(b * 1024 + s0)) * 128
                        + (w * 16 + lr) * 128 + lg * 16;
    rb[0] = *(const bfrag*)(rbase);
    rb[1] = *(const bfrag*)(rbase + 64);
  }

  // ---- prologue: stage chunk(0) + coeff(0) ----
  if (w < 4) gload16(csrc, smem + woff);
  gload16(ksrc, smem + 8192 + woff);
  __syncthreads();

  ffrag acc[8] = {};   // [kt]: k = kt*16+lr, res = s0 + w*16 + lg*4 + j

#pragma unroll 1
  for (int tc = 0; tc < 32; ++tc) {
    const int cur = tc & 1, nb = cur ^ 1;
    // ---- issue async staging for tc+1 ----
    if (tc < 31) {
      if (w < 4) gload16(csrc + (size_t)(tc + 1) * 4096, smem + nb * 4096 + woff);
      gload16(ksrc + (size_t)(tc + 1) * 8192, smem + 8192 + nb * 8192 + woff);
    }

    // ---- L-phase(tc): D[chk32][res16] -> tanh -> pk regs ----
    const char* rwc = smem + cur * 4096;
    uint2 pk[2];   // [ts]
#pragma unroll
    for (int ts = 0; ts < 2; ++ts) {
      ffrag la = {};
#pragma unroll
      for (int ks = 0; ks < 2; ++ks) {
        const int arow = ts * 16 + lr;
        bfrag a = *(const bfrag*)(rwc + arow * 128 + (((ks * 4 + lg) ^ (arow & 7)) << 4));
        la = MFMA(a, rb[ks], la);
      }
      pk[ts].x = cvtpk(ftanh(la[0]), ftanh(la[1]));
      pk[ts].y = cvtpk(ftanh(la[2]), ftanh(la[3]));
    }
    // concatenated D-tiles == K=32 A-frag (slot-matched layout)
    uint4 au; au.x = pk[0].x; au.y = pk[0].y; au.z = pk[1].x; au.w = pk[1].y;
    const bfrag af = __builtin_bit_cast(bfrag, au);

    // ---- GEMM(tc): acc[kt] += L x coeff, K=32, A from registers ----
    const char* rlc = smem + 8192 + cur * 8192 + lg * 256 + lr * 16;
#pragma unroll
    for (int kt = 0; kt < 8; ++kt) {
      bfrag bk = *(const bfrag*)(rlc + kt * 1024);
      acc[kt] = MFMA(af, bk, acc[kt]);
    }
    __syncthreads();   // staging drained + buffers retired (ONE barrier/iter)
  }

  // ---- epilogue (wave-local): z[res] = sum_k wh[k] * tanh(acc + add) ----
  // lane holds acc[kt][j]: k = kt*16+lr, res = s0 + w*16 + lg*4 + j
  float whs[8];
#pragma unroll
  for (int kt = 0; kt < 8; ++kt) whs[kt] = wh[kt * 16 + lr];

  // addterm fragged read: res -> tc_a = strip*4+(w>>1); c = (w&1)*16+lg*4+j
  //   -> g_a = lg, e_a = (w&1)*4 + j; lr_k = lr
  const char* abase = (const char*)addterm + (size_t)b * 262144
                      + (size_t)(strip * 4 + (w >> 1)) * 8192
                      + lg * 256 + lr * 16 + (w & 1) * 8;
  float zs[4] = {0, 0, 0, 0};
#pragma unroll
  for (int kt = 0; kt < 8; ++kt) {
    uint2 av = *(const uint2*)(abase + kt * 1024);
    const float whk = whs[kt];
    zs[0] += whk * ftanh(acc[kt][0] + b2f((unsigned short)(av.x & 0xFFFF)));
    zs[1] += whk * ftanh(acc[kt][1] + b2f((unsigned short)(av.x >> 16)));
    zs[2] += whk * ftanh(acc[kt][2] + b2f((unsigned short)(av.y & 0xFFFF)));
    zs[3] += whk * ftanh(acc[kt][3] + b2f((unsigned short)(av.y >> 16)));
  }
#pragma unroll
  for (int j = 0; j < 4; ++j) {
    zs[j] += __shfl_xor(zs[j], 1);
    zs[j] += __shfl_xor(zs[j], 2);
    zs[j] += __shfl_xor(zs[j], 4);
    zs[j] += __shfl_xor(zs[j], 8);
  }
  if (lr == 0) {
#pragma unroll
    for (int j = 0; j < 4; ++j)
      zout[(size_t)b * 1024 + s0 + w * 16 + lg * 4 + j] = zs[j];
  }
}

// ---------------------------------------------------------------------------
// final: block (b, side), 1024 threads: softmax(z) -> weighted seq sum -> out
// ---------------------------------------------------------------------------
__global__ __launch_bounds__(1024) void final_kernel(
    const float* __restrict__ review, const float* __restrict__ post,
    const float* __restrict__ zp, const float* __restrict__ zr,
    float* __restrict__ out)
{
  const int b = blockIdx.x, side = blockIdx.y, tid = threadIdx.x;
  const int wid = tid >> 6, lane = tid & 63;
  __shared__ float zl[1024];
  __shared__ float red[16];
  __shared__ float cacc[16][64];

  const float* z = (side == 0) ? zp : zr;
  const float* seq = (side == 0) ? post : review;

  float v = z[(size_t)b * 1024 + tid];
  zl[tid] = v;
  float m = v;
#pragma unroll
  for (int off = 32; off; off >>= 1) m = fmaxf(m, __shfl_xor(m, off));
  if (lane == 0) red[wid] = m;
  __syncthreads();
  m = red[0];
#pragma unroll
  for (int i = 1; i < 16; ++i) m = fmaxf(m, red[i]);
  __syncthreads();

  float e = __expf(v - m);
  zl[tid] = e;
  float sm = e;
#pragma unroll
  for (int off = 32; off; off >>= 1) sm += __shfl_xor(sm, off);
  if (lane == 0) red[wid] = sm;
  __syncthreads();
  sm = red[0];
#pragma unroll
  for (int i = 1; i < 16; ++i) sm += red[i];
  const float inv = 1.0f / sm;

  const int d = lane;
  float a = 0.f;
  for (int n = wid * 64; n < wid * 64 + 64; ++n)
    a += zl[n] * seq[((size_t)(b * 1024 + n)) * 64 + d];
  cacc[wid][d] = a;
  __syncthreads();
  if (tid < 64) {
    float s = 0.f;
#pragma unroll
    for (int g = 0; g < 16; ++g) s += cacc[g][tid];
    out[b * 128 + side * 64 + tid] = s * inv;
  }
}

// ---------------------------------------------------------------------------
extern "C" void kernel_launch(void* const* d_in, const int* in_sizes, int n_in,
                              void* d_out, int out_size, void* d_ws, size_t ws_size,
                              hipStream_t stream) {
  const float* review = (const float*)d_in[0];
  const float* post   = (const float*)d_in[1];
  const float* Wl     = (const float*)d_in[2];
  const float* Wr     = (const float*)d_in[3];
  const float* Wp     = (const float*)d_in[4];
  const float* whr    = (const float*)d_in[5];
  const float* whp    = (const float*)d_in[6];
  float* out = (float*)d_out;

  char* ws = (char*)d_ws;
  unsigned short* RWb   = (unsigned short*)(ws);                        //  8 MiB
  unsigned short* Rb    = (unsigned short*)(ws + (size_t)8  * 1048576); // 16 MiB
  unsigned short* Pb    = (unsigned short*)(ws + (size_t)24 * 1048576); // 16 MiB
  unsigned short* postb = (unsigned short*)(ws + (size_t)40 * 1048576); //  8 MiB
  float* zp = (float*)(ws + (size_t)48 * 1048576);                      // 256 KiB
  float* zr = (float*)(ws + (size_t)48 * 1048576 + 262144);             // 256 KiB

  prep_kernel<<<dim3(8, 64, 2), dim3(256), 0, stream>>>(
      review, post, Wl, Wr, Wp, RWb, Rb, Pb, postb);
  hz_kernel<<<dim3(1024), dim3(512), 0, stream>>>(
      RWb, Rb, Pb, postb, whp, whr, zp, zr);
  final_kernel<<<dim3(64, 2), dim3(1024), 0, stream>>>(
      review, post, zp, zr, out);
}

// Round 12
// 99.290 us; speedup vs baseline: 1.8602x; 1.1745x over previous
//
#include <hip/hip_runtime.h>
#include <hip/hip_bf16.h>

// Problem constants: B=64, T=N=1024, d=64, k=128.

typedef __attribute__((ext_vector_type(8))) short bfrag;    // 8 x bf16 (4 VGPRs)
typedef __attribute__((ext_vector_type(4))) float ffrag;    // 4 x f32 acc

typedef const __attribute__((address_space(1))) unsigned GAS_U;
typedef __attribute__((address_space(3))) unsigned LAS_U;

__device__ __forceinline__ void gload16(const void* g, void* l) {
  // async global->LDS, 16B per lane; LDS dest = wave-uniform base + lane*16
  __builtin_amdgcn_global_load_lds((GAS_U*)g, (LAS_U*)l, 16, 0, 0);
}

__device__ __forceinline__ unsigned short f2b(float f) {
  unsigned u = __builtin_bit_cast(unsigned, f);
  u += 0x7FFFu + ((u >> 16) & 1u);          // RNE f32 -> bf16 (finite inputs)
  return (unsigned short)(u >> 16);
}
__device__ __forceinline__ float b2f(unsigned short h) {
  return __builtin_bit_cast(float, (unsigned)h << 16);
}
__device__ __forceinline__ float ftanh(float x) {
  // tanh(x) = 1 - 2/(2^(x*2*log2e)+1); ~1e-6 abs err
  float e = __builtin_amdgcn_exp2f(x * 2.88539008177792681f);
  return fmaf(-2.0f, __builtin_amdgcn_rcpf(e + 1.0f), 1.0f);
}
// packed bf16 pair {lo in low16, hi in high16}, RNE, single instruction
__device__ __forceinline__ unsigned cvtpk(float lo, float hi) {
  unsigned r;
  asm("v_cvt_pk_bf16_f32 %0, %1, %2" : "=v"(r) : "v"(lo), "v"(hi));
  return r;
}

#define MFMA(a, b, c) __builtin_amdgcn_mfma_f32_16x16x32_bf16((a), (b), (c), 0, 0, 0)

// Fragged coeff/addterm layout (K=32 slot-matched to hz's L-phase D-tiles):
//   element (k, t): tc=t>>5; c=t&31; ts'=c>>4; g=(c>>2)&3; j_c=c&3;
//                   e = ts'*4 + j_c; kt=k>>4; lr_k=k&15
//   byte = b*262144 + tc*8192 + kt*1024 + g*256 + lr_k*16 + e*2
// (identical to r11 — hz reads unchanged; prep now WRITES it with packed
//  uint2 stores by computing D with t on the row(reg) axis, k on col(lane))

// ---------------------------------------------------------------------------
// prep v12: operand-swapped GEMMs -> packed uint2 global stores.
//   RWb = bf16(review@Wl) [B,T,64] row-major
//   Rb/Pb = fragged layout above; postb = bf16(post) [B,N,64]
// ---------------------------------------------------------------------------
__global__ __launch_bounds__(256) void prep_kernel(
    const float* __restrict__ review, const float* __restrict__ post,
    const float* __restrict__ Wl, const float* __restrict__ Wr,
    const float* __restrict__ Wp,
    unsigned short* __restrict__ RWb, unsigned short* __restrict__ Rb,
    unsigned short* __restrict__ Pb, unsigned short* __restrict__ postb)
{
  const int chunk = blockIdx.x, b = blockIdx.y, side = blockIdx.z;
  const int tid = threadIdx.x, lane = tid & 63, w = tid >> 6;
  const int lr = lane & 15, lg = lane >> 4;
  const int r0 = chunk * 128;

  __shared__ __align__(16) unsigned short seqs[128][72];  // seq rows [r][d]
  __shared__ __align__(16) unsigned short wgt[128][72];   // Wr or Wp [k][d]
  __shared__ __align__(16) unsigned short wlt[64][72];    // Wl^T [i][d]

  const float* seq = (side == 0) ? review : post;
#pragma unroll
  for (int jj = 0; jj < 8; ++jj) {
    int e = tid + jj * 256;            // r = e>>4, d4 = (e&15)*4
    int r = e >> 4, d4 = (e & 15) * 4;
    float4 v = *(const float4*)(seq + ((size_t)(b * 1024 + r0 + r)) * 64 + d4);
    unsigned lo = ((unsigned)f2b(v.y) << 16) | f2b(v.x);
    unsigned hi = ((unsigned)f2b(v.w) << 16) | f2b(v.z);
    *(uint2*)&seqs[r][d4] = make_uint2(lo, hi);
    if (side == 1)
      *(uint2*)(postb + ((size_t)(b * 1024 + r0 + r)) * 64 + d4) = make_uint2(lo, hi);
  }
  const float* wkd = (side == 0) ? Wr : Wp;
#pragma unroll
  for (int jj = 0; jj < 8; ++jj) {
    int e = tid + jj * 256;
    int k = e >> 4, d4 = (e & 15) * 4;
    float4 v = *(const float4*)(wkd + k * 64 + d4);
    unsigned lo = ((unsigned)f2b(v.y) << 16) | f2b(v.x);
    unsigned hi = ((unsigned)f2b(v.w) << 16) | f2b(v.z);
    *(uint2*)&wgt[k][d4] = make_uint2(lo, hi);
  }
  if (side == 0) {
    for (int i = tid; i < 64 * 64; i += 256) {
      int d = i >> 6, c = i & 63;
      wlt[c][d] = f2b(Wl[d * 64 + c]);
    }
  }
  __syncthreads();

  if (side == 0) {
    // RW^T tiles: D[i2][t] with A = wlt rows i2, B = seqs rows t.
    // Wave w owns t-tiles {2w, 2w+1}; element: i2 = is*16+lg*4+j (row),
    // t = tile*16+lr (col) -> 4 consecutive i2 per quad -> uint2 store.
    ffrag acc[2][4] = {};   // [tt][is]
#pragma unroll
    for (int ks = 0; ks < 2; ++ks)
#pragma unroll
      for (int is = 0; is < 4; ++is) {
        bfrag a = *(const bfrag*)&wlt[is * 16 + lr][ks * 32 + lg * 8];
#pragma unroll
        for (int tt = 0; tt < 2; ++tt) {
          bfrag bb = *(const bfrag*)&seqs[(w * 2 + tt) * 16 + lr][ks * 32 + lg * 8];
          acc[tt][is] = MFMA(a, bb, acc[tt][is]);
        }
      }
#pragma unroll
    for (int tt = 0; tt < 2; ++tt) {
      const int t = r0 + (w * 2 + tt) * 16 + lr;
      char* rowb = (char*)RWb + ((size_t)(b * 1024 + t)) * 128 + lg * 8;
#pragma unroll
      for (int is = 0; is < 4; ++is) {
        uint2 pkv;
        pkv.x = cvtpk(acc[tt][is][0], acc[tt][is][1]);
        pkv.y = cvtpk(acc[tt][is][2], acc[tt][is][3]);
        *(uint2*)(rowb + is * 32) = pkv;
      }
    }
  }
  {
    // R/P tiles: D[t][k] with A = seqs rows t, B = wgt rows k.
    // Wave w owns t-tiles {2w, 2w+1}; element: t = tile*16+lg*4+j (row),
    // k = kt*16+lr (col) -> 4 consecutive t per quad == e-axis -> uint2.
    ffrag acc[2][8] = {};   // [tt][kt]
#pragma unroll
    for (int ks = 0; ks < 2; ++ks)
#pragma unroll
      for (int tt = 0; tt < 2; ++tt) {
        bfrag a = *(const bfrag*)&seqs[(w * 2 + tt) * 16 + lr][ks * 32 + lg * 8];
#pragma unroll
        for (int kt = 0; kt < 8; ++kt) {
          bfrag bb = *(const bfrag*)&wgt[kt * 16 + lr][ks * 32 + lg * 8];
          acc[tt][kt] = MFMA(a, bb, acc[tt][kt]);
        }
      }
    // store: tc = chunk*4 + w; ts' = tt; g = lg; lr_k = lr; e = tt*4 + j
    char* dstb = (char*)((side == 0) ? Rb : Pb) + (size_t)b * 262144
                 + (size_t)(chunk * 4 + w) * 8192 + lg * 256 + lr * 16;
#pragma unroll
    for (int tt = 0; tt < 2; ++tt)
#pragma unroll
      for (int kt = 0; kt < 8; ++kt) {
        uint2 pkv;
        pkv.x = cvtpk(acc[tt][kt][0], acc[tt][kt][1]);
        pkv.y = cvtpk(acc[tt][kt][2], acc[tt][kt][3]);
        *(uint2*)(dstb + kt * 1024 + tt * 8) = pkv;
      }
  }
}

// ---------------------------------------------------------------------------
// hz v11 (UNCHANGED from round 11 — best measured: 71 µs, no spill,
// 0 bank conflicts): wave-independent, register-direct K=32 L feed.
// ---------------------------------------------------------------------------
__global__ __launch_bounds__(512, 4) void hz_kernel(
    const unsigned short* __restrict__ RWb, const unsigned short* __restrict__ Rb,
    const unsigned short* __restrict__ Pb, const unsigned short* __restrict__ postb,
    const float* __restrict__ whp, const float* __restrict__ whr,
    float* __restrict__ zp, float* __restrict__ zr)
{
  const int orig = blockIdx.x;
  const int swz = (orig & 7) * 128 + (orig >> 3);   // XCD-chunked, bijective
  const int strip = swz & 7, pair = swz >> 3;
  const int b = pair & 63, role = pair >> 6;
  const int s0 = strip * 128;
  const int tid = threadIdx.x, lane = tid & 63, w = tid >> 6;
  const int lr = lane & 15, lg = lane >> 4;

  const unsigned short* resident = role ? RWb : postb;
  const unsigned short* chunkseq = role ? postb : RWb;
  const unsigned short* coeff    = role ? Pb : Rb;
  const unsigned short* addterm  = role ? Rb : Pb;
  const float* wh                = role ? whr : whp;
  float* zout                    = role ? zr : zp;

  __shared__ __align__(16) char smem[24576];
  const int woff = w << 10;   // wave-uniform LDS staging base offset

  const int crow = tid >> 3, cslot = tid & 7;
  const char* csrc = (const char*)chunkseq + (size_t)b * 131072
                     + crow * 128 + ((cslot ^ (crow & 7)) << 4);   // + tc*4096
  const char* ksrc = (const char*)coeff + (size_t)b * 262144 + tid * 16; // + tc*8192

  // ---- loop-invariant resident B-frags (8 VGPRs): rows res = w*16+lr ----
  bfrag rb[2];
  {
    const char* rbase = (const char*)resident + ((size_t)(b * 1024 + s0)) * 128
                        + (w * 16 + lr) * 128 + lg * 16;
    rb[0] = *(const bfrag*)(rbase);
    rb[1] = *(const bfrag*)(rbase + 64);
  }

  // ---- prologue: stage chunk(0) + coeff(0) ----
  if (w < 4) gload16(csrc, smem + woff);
  gload16(ksrc, smem + 8192 + woff);
  __syncthreads();

  ffrag acc[8] = {};   // [kt]: k = kt*16+lr, res = s0 + w*16 + lg*4 + j

#pragma unroll 1
  for (int tc = 0; tc < 32; ++tc) {
    const int cur = tc & 1, nb = cur ^ 1;
    if (tc < 31) {
      if (w < 4) gload16(csrc + (size_t)(tc + 1) * 4096, smem + nb * 4096 + woff);
      gload16(ksrc + (size_t)(tc + 1) * 8192, smem + 8192 + nb * 8192 + woff);
    }

    // ---- L-phase(tc): D[chk32][res16] -> tanh -> pk regs ----
    const char* rwc = smem + cur * 4096;
    uint2 pk[2];   // [ts]
#pragma unroll
    for (int ts = 0; ts < 2; ++ts) {
      ffrag la = {};
#pragma unroll
      for (int ks = 0; ks < 2; ++ks) {
        const int arow = ts * 16 + lr;
        bfrag a = *(const bfrag*)(rwc + arow * 128 + (((ks * 4 + lg) ^ (arow & 7)) << 4));
        la = MFMA(a, rb[ks], la);
      }
      pk[ts].x = cvtpk(ftanh(la[0]), ftanh(la[1]));
      pk[ts].y = cvtpk(ftanh(la[2]), ftanh(la[3]));
    }
    // concatenated D-tiles == K=32 A-frag (slot-matched layout)
    uint4 au; au.x = pk[0].x; au.y = pk[0].y; au.z = pk[1].x; au.w = pk[1].y;
    const bfrag af = __builtin_bit_cast(bfrag, au);

    // ---- GEMM(tc): acc[kt] += L x coeff, K=32, A from registers ----
    const char* rlc = smem + 8192 + cur * 8192 + lg * 256 + lr * 16;
#pragma unroll
    for (int kt = 0; kt < 8; ++kt) {
      bfrag bk = *(const bfrag*)(rlc + kt * 1024);
      acc[kt] = MFMA(af, bk, acc[kt]);
    }
    __syncthreads();   // staging drained + buffers retired (ONE barrier/iter)
  }

  // ---- epilogue (wave-local): z[res] = sum_k wh[k] * tanh(acc + add) ----
  float whs[8];
#pragma unroll
  for (int kt = 0; kt < 8; ++kt) whs[kt] = wh[kt * 16 + lr];

  const char* abase = (const char*)addterm + (size_t)b * 262144
                      + (size_t)(strip * 4 + (w >> 1)) * 8192
                      + lg * 256 + lr * 16 + (w & 1) * 8;
  float zs[4] = {0, 0, 0, 0};
#pragma unroll
  for (int kt = 0; kt < 8; ++kt) {
    uint2 av = *(const uint2*)(abase + kt * 1024);
    const float whk = whs[kt];
    zs[0] += whk * ftanh(acc[kt][0] + b2f((unsigned short)(av.x & 0xFFFF)));
    zs[1] += whk * ftanh(acc[kt][1] + b2f((unsigned short)(av.x >> 16)));
    zs[2] += whk * ftanh(acc[kt][2] + b2f((unsigned short)(av.y & 0xFFFF)));
    zs[3] += whk * ftanh(acc[kt][3] + b2f((unsigned short)(av.y >> 16)));
  }
#pragma unroll
  for (int j = 0; j < 4; ++j) {
    zs[j] += __shfl_xor(zs[j], 1);
    zs[j] += __shfl_xor(zs[j], 2);
    zs[j] += __shfl_xor(zs[j], 4);
    zs[j] += __shfl_xor(zs[j], 8);
  }
  if (lr == 0) {
#pragma unroll
    for (int j = 0; j < 4; ++j)
      zout[(size_t)b * 1024 + s0 + w * 16 + lg * 4 + j] = zs[j];
  }
}

// ---------------------------------------------------------------------------
// final: block (b, side), 1024 threads: softmax(z) -> weighted seq sum -> out
// ---------------------------------------------------------------------------
__global__ __launch_bounds__(1024) void final_kernel(
    const float* __restrict__ review, const float* __restrict__ post,
    const float* __restrict__ zp, const float* __restrict__ zr,
    float* __restrict__ out)
{
  const int b = blockIdx.x, side = blockIdx.y, tid = threadIdx.x;
  const int wid = tid >> 6, lane = tid & 63;
  __shared__ float zl[1024];
  __shared__ float red[16];
  __shared__ float cacc[16][64];

  const float* z = (side == 0) ? zp : zr;
  const float* seq = (side == 0) ? post : review;

  float v = z[(size_t)b * 1024 + tid];
  zl[tid] = v;
  float m = v;
#pragma unroll
  for (int off = 32; off; off >>= 1) m = fmaxf(m, __shfl_xor(m, off));
  if (lane == 0) red[wid] = m;
  __syncthreads();
  m = red[0];
#pragma unroll
  for (int i = 1; i < 16; ++i) m = fmaxf(m, red[i]);
  __syncthreads();

  float e = __expf(v - m);
  zl[tid] = e;
  float sm = e;
#pragma unroll
  for (int off = 32; off; off >>= 1) sm += __shfl_xor(sm, off);
  if (lane == 0) red[wid] = sm;
  __syncthreads();
  sm = red[0];
#pragma unroll
  for (int i = 1; i < 16; ++i) sm += red[i];
  const float inv = 1.0f / sm;

  const int d = lane;
  float a = 0.f;
  for (int n = wid * 64; n < wid * 64 + 64; ++n)
    a += zl[n] * seq[((size_t)(b * 1024 + n)) * 64 + d];
  cacc[wid][d] = a;
  __syncthreads();
  if (tid < 64) {
    float s = 0.f;
#pragma unroll
    for (int g = 0; g < 16; ++g) s += cacc[g][tid];
    out[b * 128 + side * 64 + tid] = s * inv;
  }
}

// ---------------------------------------------------------------------------
extern "C" void kernel_launch(void* const* d_in, const int* in_sizes, int n_in,
                              void* d_out, int out_size, void* d_ws, size_t ws_size,
                              hipStream_t stream) {
  const float* review = (const float*)d_in[0];
  const float* post   = (const float*)d_in[1];
  const float* Wl     = (const float*)d_in[2];
  const float* Wr     = (const float*)d_in[3];
  const float* Wp     = (const float*)d_in[4];
  const float* whr    = (const float*)d_in[5];
  const float* whp    = (const float*)d_in[6];
  float* out = (float*)d_out;

  char* ws = (char*)d_ws;
  unsigned short* RWb   = (unsigned short*)(ws);                        //  8 MiB
  unsigned short* Rb    = (unsigned short*)(ws + (size_t)8  * 1048576); // 16 MiB
  unsigned short* Pb    = (unsigned short*)(ws + (size_t)24 * 1048576); // 16 MiB
  unsigned short* postb = (unsigned short*)(ws + (size_t)40 * 1048576); //  8 MiB
  float* zp = (float*)(ws + (size_t)48 * 1048576);                      // 256 KiB
  float* zr = (float*)(ws + (size_t)48 * 1048576 + 262144);             // 256 KiB

  prep_kernel<<<dim3(8, 64, 2), dim3(256), 0, stream>>>(
      review, post, Wl, Wr, Wp, RWb, Rb, Pb, postb);
  hz_kernel<<<dim3(1024), dim3(512), 0, stream>>>(
      RWb, Rb, Pb, postb, whp, whr, zp, zr);
  final_kernel<<<dim3(64, 2), dim3(1024), 0, stream>>>(
      review, post, zp, zr, out);
}

// Round 13
// 95.192 us; speedup vs baseline: 1.9402x; 1.0430x over previous
//
#include <hip/hip_runtime.h>
#include <hip/hip_bf16.h>

// Problem constants: B=64, T=N=1024, d=64, k=128.

typedef __attribute__((ext_vector_type(8))) short bfrag;    // 8 x bf16 (4 VGPRs)
typedef __attribute__((ext_vector_type(4))) float ffrag;    // 4 x f32 acc

typedef const __attribute__((address_space(1))) unsigned GAS_U;
typedef __attribute__((address_space(3))) unsigned LAS_U;

__device__ __forceinline__ void gload16(const void* g, void* l) {
  // async global->LDS, 16B per lane; LDS dest = wave-uniform base + lane*16
  __builtin_amdgcn_global_load_lds((GAS_U*)g, (LAS_U*)l, 16, 0, 0);
}

__device__ __forceinline__ unsigned short f2b(float f) {
  unsigned u = __builtin_bit_cast(unsigned, f);
  u += 0x7FFFu + ((u >> 16) & 1u);          // RNE f32 -> bf16 (finite inputs)
  return (unsigned short)(u >> 16);
}
__device__ __forceinline__ float b2f(unsigned short h) {
  return __builtin_bit_cast(float, (unsigned)h << 16);
}
__device__ __forceinline__ float ftanh(float x) {
  // tanh(x) = 1 - 2/(2^(x*2*log2e)+1); ~1e-6 abs err
  float e = __builtin_amdgcn_exp2f(x * 2.88539008177792681f);
  return fmaf(-2.0f, __builtin_amdgcn_rcpf(e + 1.0f), 1.0f);
}
// packed bf16 pair {lo in low16, hi in high16}, RNE, single instruction
__device__ __forceinline__ unsigned cvtpk(float lo, float hi) {
  unsigned r;
  asm("v_cvt_pk_bf16_f32 %0, %1, %2" : "=v"(r) : "v"(lo), "v"(hi));
  return r;
}

#define MFMA(a, b, c) __builtin_amdgcn_mfma_f32_16x16x32_bf16((a), (b), (c), 0, 0, 0)

// Fragged coeff/addterm layout (K=32 slot-matched to hz's L-phase D-tiles):
//   element (k, t): tc=t>>5; c=t&31; ts'=c>>4; g=(c>>2)&3; j_c=c&3;
//                   e = ts'*4 + j_c; kt=k>>4; lr_k=k&15
//   byte = b*262144 + tc*8192 + kt*1024 + g*256 + lr_k*16 + e*2

// ---------------------------------------------------------------------------
// prep v12 (unchanged): operand-swapped GEMMs -> packed uint2 global stores.
// ---------------------------------------------------------------------------
__global__ __launch_bounds__(256) void prep_kernel(
    const float* __restrict__ review, const float* __restrict__ post,
    const float* __restrict__ Wl, const float* __restrict__ Wr,
    const float* __restrict__ Wp,
    unsigned short* __restrict__ RWb, unsigned short* __restrict__ Rb,
    unsigned short* __restrict__ Pb, unsigned short* __restrict__ postb)
{
  const int chunk = blockIdx.x, b = blockIdx.y, side = blockIdx.z;
  const int tid = threadIdx.x, lane = tid & 63, w = tid >> 6;
  const int lr = lane & 15, lg = lane >> 4;
  const int r0 = chunk * 128;

  __shared__ __align__(16) unsigned short seqs[128][72];  // seq rows [r][d]
  __shared__ __align__(16) unsigned short wgt[128][72];   // Wr or Wp [k][d]
  __shared__ __align__(16) unsigned short wlt[64][72];    // Wl^T [i][d]

  const float* seq = (side == 0) ? review : post;
#pragma unroll
  for (int jj = 0; jj < 8; ++jj) {
    int e = tid + jj * 256;            // r = e>>4, d4 = (e&15)*4
    int r = e >> 4, d4 = (e & 15) * 4;
    float4 v = *(const float4*)(seq + ((size_t)(b * 1024 + r0 + r)) * 64 + d4);
    unsigned lo = ((unsigned)f2b(v.y) << 16) | f2b(v.x);
    unsigned hi = ((unsigned)f2b(v.w) << 16) | f2b(v.z);
    *(uint2*)&seqs[r][d4] = make_uint2(lo, hi);
    if (side == 1)
      *(uint2*)(postb + ((size_t)(b * 1024 + r0 + r)) * 64 + d4) = make_uint2(lo, hi);
  }
  const float* wkd = (side == 0) ? Wr : Wp;
#pragma unroll
  for (int jj = 0; jj < 8; ++jj) {
    int e = tid + jj * 256;
    int k = e >> 4, d4 = (e & 15) * 4;
    float4 v = *(const float4*)(wkd + k * 64 + d4);
    unsigned lo = ((unsigned)f2b(v.y) << 16) | f2b(v.x);
    unsigned hi = ((unsigned)f2b(v.w) << 16) | f2b(v.z);
    *(uint2*)&wgt[k][d4] = make_uint2(lo, hi);
  }
  if (side == 0) {
    for (int i = tid; i < 64 * 64; i += 256) {
      int d = i >> 6, c = i & 63;
      wlt[c][d] = f2b(Wl[d * 64 + c]);
    }
  }
  __syncthreads();

  if (side == 0) {
    // RW^T tiles: D[i2][t], A = wlt rows, B = seqs rows.
    ffrag acc[2][4] = {};   // [tt][is]
#pragma unroll
    for (int ks = 0; ks < 2; ++ks)
#pragma unroll
      for (int is = 0; is < 4; ++is) {
        bfrag a = *(const bfrag*)&wlt[is * 16 + lr][ks * 32 + lg * 8];
#pragma unroll
        for (int tt = 0; tt < 2; ++tt) {
          bfrag bb = *(const bfrag*)&seqs[(w * 2 + tt) * 16 + lr][ks * 32 + lg * 8];
          acc[tt][is] = MFMA(a, bb, acc[tt][is]);
        }
      }
#pragma unroll
    for (int tt = 0; tt < 2; ++tt) {
      const int t = r0 + (w * 2 + tt) * 16 + lr;
      char* rowb = (char*)RWb + ((size_t)(b * 1024 + t)) * 128 + lg * 8;
#pragma unroll
      for (int is = 0; is < 4; ++is) {
        uint2 pkv;
        pkv.x = cvtpk(acc[tt][is][0], acc[tt][is][1]);
        pkv.y = cvtpk(acc[tt][is][2], acc[tt][is][3]);
        *(uint2*)(rowb + is * 32) = pkv;
      }
    }
  }
  {
    // R/P tiles: D[t][k], A = seqs rows t, B = wgt rows k -> packed e-axis.
    ffrag acc[2][8] = {};   // [tt][kt]
#pragma unroll
    for (int ks = 0; ks < 2; ++ks)
#pragma unroll
      for (int tt = 0; tt < 2; ++tt) {
        bfrag a = *(const bfrag*)&seqs[(w * 2 + tt) * 16 + lr][ks * 32 + lg * 8];
#pragma unroll
        for (int kt = 0; kt < 8; ++kt) {
          bfrag bb = *(const bfrag*)&wgt[kt * 16 + lr][ks * 32 + lg * 8];
          acc[tt][kt] = MFMA(a, bb, acc[tt][kt]);
        }
      }
    // store: tc = chunk*4 + w; ts' = tt; g = lg; lr_k = lr; e = tt*4 + j
    char* dstb = (char*)((side == 0) ? Rb : Pb) + (size_t)b * 262144
                 + (size_t)(chunk * 4 + w) * 8192 + lg * 256 + lr * 16;
#pragma unroll
    for (int tt = 0; tt < 2; ++tt)
#pragma unroll
      for (int kt = 0; kt < 8; ++kt) {
        uint2 pkv;
        pkv.x = cvtpk(acc[tt][kt][0], acc[tt][kt][1]);
        pkv.y = cvtpk(acc[tt][kt][2], acc[tt][kt][3]);
        *(uint2*)(dstb + kt * 1024 + tt * 8) = pkv;
      }
  }
}

// ---------------------------------------------------------------------------
// hz v13: r11 structure, but each wave owns res-32 (2 D-tiles) x all 128 k.
// The 12 shared ds_read_b128/iter now feed 24 MFMAs (ratio 1:2), per-iter
// staging/addressing amortized 2x, per-CU staging volume halved.
// 512-thread blocks (8 waves) cover res-256; grid 512 (2 blocks/CU).
// LDS (24576 B): rw dbuf @0/@4096 [32 rows][128B] chunk (pre-swz global src)
//                rl dbuf @8192/@16384 fragged coeff (LINEAR gload src)
// Regs: acc 64 AGPR + rb 16 + pk 8 + addr ~30 -> ~116 unified <= 128 @4/SIMD.
// ---------------------------------------------------------------------------
__global__ __launch_bounds__(512, 4) void hz_kernel(
    const unsigned short* __restrict__ RWb, const unsigned short* __restrict__ Rb,
    const unsigned short* __restrict__ Pb, const unsigned short* __restrict__ postb,
    const float* __restrict__ whp, const float* __restrict__ whr,
    float* __restrict__ zp, float* __restrict__ zr)
{
  const int orig = blockIdx.x;
  const int swz = (orig & 7) * 64 + (orig >> 3);   // XCD-chunked, 512 = 8*64
  const int strip = swz & 3, pair = swz >> 2;
  const int b = pair & 63, role = pair >> 6;
  const int s0 = strip * 256;
  const int tid = threadIdx.x, lane = tid & 63, w = tid >> 6;
  const int lr = lane & 15, lg = lane >> 4;

  const unsigned short* resident = role ? RWb : postb;
  const unsigned short* chunkseq = role ? postb : RWb;
  const unsigned short* coeff    = role ? Pb : Rb;
  const unsigned short* addterm  = role ? Rb : Pb;
  const float* wh                = role ? whr : whp;
  float* zout                    = role ? zr : zp;

  __shared__ __align__(16) char smem[24576];
  const int woff = w << 10;   // wave-uniform LDS staging base offset

  // chunk staging source (pre-swizzled so linear dest is XOR-swizzled);
  // waves 0-3 issue (4KB per tc)
  const int crow = tid >> 3, cslot = tid & 7;
  const char* csrc = (const char*)chunkseq + (size_t)b * 131072
                     + crow * 128 + ((cslot ^ (crow & 7)) << 4);   // + tc*4096
  // coeff staging source: fragged layout == LDS layout -> pure linear,
  // all 8 waves (8KB per tc)
  const char* ksrc = (const char*)coeff + (size_t)b * 262144 + tid * 16; // + tc*8192

  // ---- loop-invariant resident B-frags (16 VGPRs): rows res = w*32+rs*16+lr
  bfrag rb[2][2];   // [ks][rs]
  {
    const char* rbase = (const char*)resident + ((size_t)(b * 1024 + s0)) * 128
                        + (w * 32 + lr) * 128 + lg * 16;
#pragma unroll
    for (int rs = 0; rs < 2; ++rs) {
      rb[0][rs] = *(const bfrag*)(rbase + rs * 2048);
      rb[1][rs] = *(const bfrag*)(rbase + rs * 2048 + 64);
    }
  }

  // ---- prologue: stage chunk(0) + coeff(0) ----
  if (w < 4) gload16(csrc, smem + woff);
  gload16(ksrc, smem + 8192 + woff);
  __syncthreads();

  ffrag acc[2][8] = {};   // [rs][kt]: k = kt*16+lr, res = s0+w*32+rs*16+lg*4+j

#pragma unroll 1
  for (int tc = 0; tc < 32; ++tc) {
    const int cur = tc & 1, nb = cur ^ 1;
    // ---- issue async staging for tc+1 ----
    if (tc < 31) {
      if (w < 4) gload16(csrc + (size_t)(tc + 1) * 4096, smem + nb * 4096 + woff);
      gload16(ksrc + (size_t)(tc + 1) * 8192, smem + 8192 + nb * 8192 + woff);
    }

    // ---- L-phase(tc): D[chk32][res16] x2 rs -> tanh -> pk regs ----
    const char* rwc = smem + cur * 4096;
    uint2 pk[2][2];   // [ts][rs]
#pragma unroll
    for (int ts = 0; ts < 2; ++ts) {
      ffrag la0 = {}, la1 = {};
#pragma unroll
      for (int ks = 0; ks < 2; ++ks) {
        const int arow = ts * 16 + lr;
        bfrag a = *(const bfrag*)(rwc + arow * 128 + (((ks * 4 + lg) ^ (arow & 7)) << 4));
        la0 = MFMA(a, rb[ks][0], la0);
        la1 = MFMA(a, rb[ks][1], la1);
      }
      pk[ts][0].x = cvtpk(ftanh(la0[0]), ftanh(la0[1]));
      pk[ts][0].y = cvtpk(ftanh(la0[2]), ftanh(la0[3]));
      pk[ts][1].x = cvtpk(ftanh(la1[0]), ftanh(la1[1]));
      pk[ts][1].y = cvtpk(ftanh(la1[2]), ftanh(la1[3]));
    }
    // concatenated D-tiles == K=32 A-frags (slot-matched layout)
    uint4 a0u; a0u.x = pk[0][0].x; a0u.y = pk[0][0].y; a0u.z = pk[1][0].x; a0u.w = pk[1][0].y;
    uint4 a1u; a1u.x = pk[0][1].x; a1u.y = pk[0][1].y; a1u.z = pk[1][1].x; a1u.w = pk[1][1].y;
    const bfrag af0 = __builtin_bit_cast(bfrag, a0u);
    const bfrag af1 = __builtin_bit_cast(bfrag, a1u);

    // ---- GEMM(tc): acc[rs][kt] += L x coeff, K=32, A from registers ----
    const char* rlc = smem + 8192 + cur * 8192 + lg * 256 + lr * 16;
#pragma unroll
    for (int kt = 0; kt < 8; ++kt) {
      bfrag bk = *(const bfrag*)(rlc + kt * 1024);
      acc[0][kt] = MFMA(af0, bk, acc[0][kt]);
      acc[1][kt] = MFMA(af1, bk, acc[1][kt]);
    }
    __syncthreads();   // staging drained + buffers retired (ONE barrier/iter)
  }

  // ---- epilogue (wave-local): z[res] = sum_k wh[k] * tanh(acc + add) ----
  // lane holds acc[rs][kt][j]: k = kt*16+lr, res = s0+w*32+rs*16+lg*4+j
  float whs[8];
#pragma unroll
  for (int kt = 0; kt < 8; ++kt) whs[kt] = wh[kt * 16 + lr];

  // addterm fragged read: tc_a = strip*8 + w; ts' = rs; g = lg; e = rs*4+j
  const char* abase = (const char*)addterm + (size_t)b * 262144
                      + (size_t)(strip * 8 + w) * 8192
                      + lg * 256 + lr * 16;
  float zs[2][4] = {};
#pragma unroll
  for (int rs = 0; rs < 2; ++rs)
#pragma unroll
    for (int kt = 0; kt < 8; ++kt) {
      uint2 av = *(const uint2*)(abase + kt * 1024 + rs * 8);
      const float whk = whs[kt];
      zs[rs][0] += whk * ftanh(acc[rs][kt][0] + b2f((unsigned short)(av.x & 0xFFFF)));
      zs[rs][1] += whk * ftanh(acc[rs][kt][1] + b2f((unsigned short)(av.x >> 16)));
      zs[rs][2] += whk * ftanh(acc[rs][kt][2] + b2f((unsigned short)(av.y & 0xFFFF)));
      zs[rs][3] += whk * ftanh(acc[rs][kt][3] + b2f((unsigned short)(av.y >> 16)));
    }
#pragma unroll
  for (int rs = 0; rs < 2; ++rs)
#pragma unroll
    for (int j = 0; j < 4; ++j) {
      float v = zs[rs][j];
      v += __shfl_xor(v, 1);
      v += __shfl_xor(v, 2);
      v += __shfl_xor(v, 4);
      v += __shfl_xor(v, 8);
      if (lr == 0)
        zout[(size_t)b * 1024 + s0 + w * 32 + rs * 16 + lg * 4 + j] = v;
    }
}

// ---------------------------------------------------------------------------
// final: block (b, side), 1024 threads: softmax(z) -> weighted seq sum -> out
// ---------------------------------------------------------------------------
__global__ __launch_bounds__(1024) void final_kernel(
    const float* __restrict__ review, const float* __restrict__ post,
    const float* __restrict__ zp, const float* __restrict__ zr,
    float* __restrict__ out)
{
  const int b = blockIdx.x, side = blockIdx.y, tid = threadIdx.x;
  const int wid = tid >> 6, lane = tid & 63;
  __shared__ float zl[1024];
  __shared__ float red[16];
  __shared__ float cacc[16][64];

  const float* z = (side == 0) ? zp : zr;
  const float* seq = (side == 0) ? post : review;

  float v = z[(size_t)b * 1024 + tid];
  zl[tid] = v;
  float m = v;
#pragma unroll
  for (int off = 32; off; off >>= 1) m = fmaxf(m, __shfl_xor(m, off));
  if (lane == 0) red[wid] = m;
  __syncthreads();
  m = red[0];
#pragma unroll
  for (int i = 1; i < 16; ++i) m = fmaxf(m, red[i]);
  __syncthreads();

  float e = __expf(v - m);
  zl[tid] = e;
  float sm = e;
#pragma unroll
  for (int off = 32; off; off >>= 1) sm += __shfl_xor(sm, off);
  if (lane == 0) red[wid] = sm;
  __syncthreads();
  sm = red[0];
#pragma unroll
  for (int i = 1; i < 16; ++i) sm += red[i];
  const float inv = 1.0f / sm;

  const int d = lane;
  float a = 0.f;
  for (int n = wid * 64; n < wid * 64 + 64; ++n)
    a += zl[n] * seq[((size_t)(b * 1024 + n)) * 64 + d];
  cacc[wid][d] = a;
  __syncthreads();
  if (tid < 64) {
    float s = 0.f;
#pragma unroll
    for (int g = 0; g < 16; ++g) s += cacc[g][tid];
    out[b * 128 + side * 64 + tid] = s * inv;
  }
}

// ---------------------------------------------------------------------------
extern "C" void kernel_launch(void* const* d_in, const int* in_sizes, int n_in,
                              void* d_out, int out_size, void* d_ws, size_t ws_size,
                              hipStream_t stream) {
  const float* review = (const float*)d_in[0];
  const float* post   = (const float*)d_in[1];
  const float* Wl     = (const float*)d_in[2];
  const float* Wr     = (const float*)d_in[3];
  const float* Wp     = (const float*)d_in[4];
  const float* whr    = (const float*)d_in[5];
  const float* whp    = (const float*)d_in[6];
  float* out = (float*)d_out;

  char* ws = (char*)d_ws;
  unsigned short* RWb   = (unsigned short*)(ws);                        //  8 MiB
  unsigned short* Rb    = (unsigned short*)(ws + (size_t)8  * 1048576); // 16 MiB
  unsigned short* Pb    = (unsigned short*)(ws + (size_t)24 * 1048576); // 16 MiB
  unsigned short* postb = (unsigned short*)(ws + (size_t)40 * 1048576); //  8 MiB
  float* zp = (float*)(ws + (size_t)48 * 1048576);                      // 256 KiB
  float* zr = (float*)(ws + (size_t)48 * 1048576 + 262144);             // 256 KiB

  prep_kernel<<<dim3(8, 64, 2), dim3(256), 0, stream>>>(
      review, post, Wl, Wr, Wp, RWb, Rb, Pb, postb);
  hz_kernel<<<dim3(512), dim3(512), 0, stream>>>(
      RWb, Rb, Pb, postb, whp, whr, zp, zr);
  final_kernel<<<dim3(64, 2), dim3(1024), 0, stream>>>(
      review, post, zp, zr, out);
}